// Round 23
// baseline (231.999 us; speedup 1.0000x reference)
//
#include <hip/hip_runtime.h>
#include <cstdint>
#include <cstddef>

#define B_ 2
#define L_ 2048
#define D_ 1024
#define H_ 16
#define DH 64

typedef __attribute__((ext_vector_type(8))) short bf16x8;
typedef __attribute__((ext_vector_type(4))) float f32x4;
typedef unsigned short u16;

__device__ inline u16 f2bf(float f) {
  unsigned u = __builtin_bit_cast(unsigned, f);
  u += 0x7fffu + ((u >> 16) & 1u);
  return (u16)(u >> 16);
}

__device__ inline float bf2f(u16 x) {
  return __builtin_bit_cast(float, (unsigned)x << 16);
}

// DPP lane-move (VALU pipe). Returns src shuffled per CTRL; full masks.
template <int CTRL>
__device__ inline float dpp_mov(float x) {
  int t = __builtin_amdgcn_update_dpp(0, __builtin_bit_cast(int, x), CTRL, 0xf, 0xf, true);
  return __builtin_bit_cast(float, t);
}

// global -> LDS direct (16B per lane). Staging layout must be linear in lane.
#define GLDS16(ldst, gsrc)                                              \
  __builtin_amdgcn_global_load_lds(                                    \
      (const __attribute__((address_space(1))) void*)(gsrc),           \
      (__attribute__((address_space(3))) void*)(ldst), 16, 0, 0)

// STP row helpers
__device__ inline void stp_upd(float4& z, const float4 r, const float4 g,
                               const float4 wlc, float vv,
                               float kx, float ky, float kz, float kw) {
  z.x = fmaf(r.x, z.x, fmaf(g.x * vv, kx, wlc.x));
  z.y = fmaf(r.y, z.y, fmaf(g.y * vv, ky, wlc.y));
  z.z = fmaf(r.z, z.z, fmaf(g.z * vv, kz, wlc.z));
  z.w = fmaf(r.w, z.w, fmaf(g.w * vv, kw, wlc.w));
}

__device__ inline void stp_upd1(float4& z, const float4 r, const float4 g,
                                float vv, float kx, float ky, float kz, float kw) {
  z.x = fmaf(r.x, z.x, (g.x * vv) * kx);
  z.y = fmaf(r.y, z.y, (g.y * vv) * ky);
  z.z = fmaf(r.z, z.z, (g.z * vv) * kz);
  z.w = fmaf(r.w, z.w, (g.w * vv) * kw);
}

__device__ inline float stp_dot(const float4 z, float qx, float qy, float qz, float qw) {
  float p = z.x * qx;
  p = fmaf(z.y, qy, p);
  p = fmaf(z.z, qz, p);
  p = fmaf(z.w, qw, p);
  return p;
}

__device__ inline float dpp_red16(float p) {
  p = p + dpp_mov<0x128>(p);  // row_ror:8 (16-lane closure)
  p = p + dpp_mov<0x124>(p);
  p = p + dpp_mov<0x122>(p);
  p = p + dpp_mov<0x121>(p);
  return p;
}

// ---------------- fused prep kernel (block-range dispatch) ----------------

__device__ inline void d_transpose(const float* __restrict__ in,
                                   u16* __restrict__ out, int R, int C,
                                   int bx, int by, float tile[32][33], int tid) {
  const int tx = tid & 31, ty = tid >> 5;
  const int c0 = bx * 32, r0 = by * 32;
#pragma unroll
  for (int j = 0; j < 4; ++j)
    tile[ty + j * 8][tx] = in[(size_t)(r0 + ty + j * 8) * C + c0 + tx];
  __syncthreads();
#pragma unroll
  for (int j = 0; j < 4; ++j)
    out[(size_t)(c0 + ty + j * 8) * R + r0 + tx] = f2bf(tile[tx][ty + j * 8]);
}

__global__ __launch_bounds__(256) void prep_fused(
    const float* __restrict__ x, u16* __restrict__ xbf,
    const float* __restrict__ wqkv_w, u16* __restrict__ wqkvT,
    const float* __restrict__ out_w, u16* __restrict__ owT,
    const float* __restrict__ g_w1, u16* __restrict__ g1T,
    const float* __restrict__ lam, const float* __restrict__ gma,
    float* __restrict__ retb, float* __restrict__ gamb,
    float* __restrict__ retb64) {
  __shared__ float tile[32][33];
  const int bid = blockIdx.x, tid = threadIdx.x;
  if (bid < 4096) {
    int i = bid * 256 + tid;
    float4 v = ((const float4*)x)[i];
    ushort4 o;
    o.x = f2bf(v.x); o.y = f2bf(v.y); o.z = f2bf(v.z); o.w = f2bf(v.w);
    ((ushort4*)xbf)[i] = o;
  } else if (bid < 7168) {
    int r = bid - 4096;
    d_transpose(wqkv_w, wqkvT, 1024, 3072, r % 96, r / 96, tile, tid);
  } else if (bid < 8192) {
    int r = bid - 7168;
    d_transpose(out_w, owT, 1024, 1024, r % 32, r / 32, tile, tid);
  } else if (bid < 8704) {
    int r = bid - 8192;
    d_transpose(g_w1, g1T, 1024, 512, r % 16, r / 16, tile, tid);
  } else {
    int i = (bid - 8704) * 256 + tid;  // 65536 total
    float l = lam[i];
    float r = 1.f / (1.f + expf(l));   // 1 - sigmoid(l)
    retb[i] = r;
    gamb[i] = gma[i] * 0.125f;         // fold k-scale into Gamma
    float r2 = r * r;                   // r^64 by 6 squarings
    float r4 = r2 * r2;
    float r8 = r4 * r4;
    float r16 = r8 * r8;
    float r32 = r16 * r16;
    retb64[i] = r32 * r32;
  }
}

// ---------------- GEMM body (C = A @ Bt^T), A: MxK bf16, Bt: NxK bf16 --------
// BK=64, chunk-swizzle (rule 21c), tileT aliases As/Bs for EPI0's v-epilogue.

struct GemmP {
  const u16* A; const u16* Bt; int M, N, K;
  const float* bias;
  u16* qb; u16* kb; u16* vtb;  // EPI 0
  float* hout;                 // EPI 1
  float* outp;                 // EPI 2
};

template <int EPI>
__device__ void gemm_body(const GemmP& p, int lin0, int nwgx, int nwgtot,
                          u16* As, u16* Bs, u16* tileT) {
  const int tid = threadIdx.x;
  const int lane = tid & 63;
  const int w = tid >> 6;
  const int wr = w >> 1, wc = w & 1;
  const int lr = lane & 15, lk = lane >> 4;
  const int cpx = nwgtot >> 3;
  const int lin = (lin0 & 7) * cpx + (lin0 >> 3);
  const int m0 = (lin / nwgx) * 128, n0 = (lin % nwgx) * 128;

  f32x4 acc[4][4];
#pragma unroll
  for (int i = 0; i < 4; ++i)
#pragma unroll
    for (int j = 0; j < 4; ++j) acc[i][j] = (f32x4){0.f, 0.f, 0.f, 0.f};

  for (int k0 = 0; k0 < p.K; k0 += 64) {
    __syncthreads();
#pragma unroll
    for (int it = 0; it < 4; ++it) {
      int idx = it * 256 + tid;               // 0..1023 chunk slots
      int row = idx >> 3;
      int ch = (idx & 7) ^ (row & 7);         // inverse-swizzled source chunk
      GLDS16(&As[idx * 8], p.A + (size_t)(m0 + row) * p.K + k0 + ch * 8);
      GLDS16(&Bs[idx * 8], p.Bt + (size_t)(n0 + row) * p.K + k0 + ch * 8);
    }
    __syncthreads();
#pragma unroll
    for (int kk = 0; kk < 2; ++kk) {
      const int slot = ((kk * 4 + lk) ^ (lr & 7)) * 8;
      bf16x8 af[4], bfr[4];
#pragma unroll
      for (int mr = 0; mr < 4; ++mr)
        af[mr] = *(const bf16x8*)&As[(wr * 64 + mr * 16 + lr) * 64 + slot];
#pragma unroll
      for (int nr = 0; nr < 4; ++nr)
        bfr[nr] = *(const bf16x8*)&Bs[(wc * 64 + nr * 16 + lr) * 64 + slot];
#pragma unroll
      for (int mr = 0; mr < 4; ++mr)
#pragma unroll
        for (int nr = 0; nr < 4; ++nr)
          acc[mr][nr] = __builtin_amdgcn_mfma_f32_16x16x32_bf16(af[mr], bfr[nr], acc[mr][nr], 0, 0, 0);
    }
  }

  if constexpr (EPI == 0) {
    if (n0 < 2048) {
#pragma unroll
      for (int mr = 0; mr < 4; ++mr)
#pragma unroll
        for (int nr = 0; nr < 4; ++nr) {
          const int col = n0 + wc * 64 + nr * 16 + lr;
#pragma unroll
          for (int rr = 0; rr < 4; ++rr) {
            const int row = m0 + wr * 64 + mr * 16 + lk * 4 + rr;
            float v = acc[mr][nr][rr] + p.bias[col];
            int which = col >> 10, hh = (col >> 6) & 15, ii = col & 63;
            int b = row >> 11, ll = row & 2047;
            size_t bi = ((size_t)(b * 16 + hh) * L_ + ll) * 64 + ii;
            if (which == 0) p.qb[bi] = f2bf(v * 0.125f);
            else            p.kb[bi] = f2bf(v);
          }
        }
    } else {
      // v region: two-pass LDS transpose in tileT (aliases As/Bs).
#pragma unroll 1
      for (int h2 = 0; h2 < 2; ++h2) {
        __syncthreads();
        if (wr == h2) {
#pragma unroll
          for (int mr = 0; mr < 4; ++mr)
#pragma unroll
            for (int nr = 0; nr < 4; ++nr) {
              const int cl = wc * 64 + nr * 16 + lr;
              const float bv = p.bias[n0 + cl];
#pragma unroll
              for (int rr = 0; rr < 4; ++rr) {
                const int rl2 = mr * 16 + lk * 4 + rr;  // 0..63
                tileT[cl * 72 + rl2] = f2bf(acc[mr][nr][rr] + bv);
              }
            }
        }
        __syncthreads();
        const int c = tid >> 1, half = tid & 1;
        const int vcol = (n0 - 2048) + c;
        const int hh = vcol >> 6, ii = vcol & 63;
        const int b = m0 >> 11;
        const int ll0 = (m0 & 2047) + h2 * 64 + half * 32;
        u16* dst = p.vtb + ((size_t)(b * 16 + hh) * 64 + ii) * L_ + ll0;
        const u16* src = &tileT[c * 72 + half * 32];
#pragma unroll
        for (int k = 0; k < 4; ++k)
          *(int4*)(dst + k * 8) = *(const int4*)(src + k * 8);
      }
    }
  } else {
#pragma unroll
    for (int mr = 0; mr < 4; ++mr)
#pragma unroll
      for (int nr = 0; nr < 4; ++nr) {
        const int col = n0 + wc * 64 + nr * 16 + lr;
#pragma unroll
        for (int rr = 0; rr < 4; ++rr) {
          const int row = m0 + wr * 64 + mr * 16 + lk * 4 + rr;
          float v = acc[mr][nr][rr] + p.bias[col];
          if constexpr (EPI == 1) {
            float g = 0.5f * v * (1.f + erff(v * 0.70710678118f));  // exact gelu
            p.hout[(size_t)row * p.N + col] = g;
          } else {
            p.outp[(size_t)row * p.N + col] = v;
          }
        }
      }
  }
}

// fused gemm<0> (768 blocks) + gemm<1> (128 blocks)
__global__ __launch_bounds__(256, 4) void gemm01_kernel(GemmP p0, GemmP p1) {
  __shared__ u16 sbuf[16384];
  u16* As = sbuf;
  u16* Bs = sbuf + 8192;
  u16* tileT = sbuf;
  const int bid = blockIdx.x;
  if (bid < 768) gemm_body<0>(p0, bid, 24, 768, As, Bs, tileT);
  else           gemm_body<1>(p1, bid - 768, 4, 128, As, Bs, tileT);
}

// standalone gemm<2> (out proj)
__global__ __launch_bounds__(256, 4) void gemm2_kernel(GemmP p) {
  __shared__ u16 As[8192];
  __shared__ u16 Bs[8192];
  const int lin0 = (int)blockIdx.x + 8 * (int)blockIdx.y;
  gemm_body<2>(p, lin0, 8, 256, As, Bs, nullptr);
}

// ---------------- gate alpha: sigmoid(h @ w2 + b2) ----------------

__global__ __launch_bounds__(256) void alpha_kernel(
    const float* __restrict__ hbuf, const float* __restrict__ w2,
    const float* __restrict__ b2, float* __restrict__ alp) {
  const int tid = threadIdx.x;
  const int row = blockIdx.x * 16 + (tid >> 4);
  const int n = tid & 15;
  const float4* h4 = (const float4*)(hbuf + (size_t)row * 512);
  float acc = 0.f;
#pragma unroll 2
  for (int kk = 0; kk < 128; ++kk) {
    float4 hv = h4[kk];
    acc = fmaf(hv.x, w2[(kk * 4 + 0) * 16 + n], acc);
    acc = fmaf(hv.y, w2[(kk * 4 + 1) * 16 + n], acc);
    acc = fmaf(hv.z, w2[(kk * 4 + 2) * 16 + n], acc);
    acc = fmaf(hv.w, w2[(kk * 4 + 3) * 16 + n], acc);
  }
  float z = acc + b2[n];
  alp[row * 16 + n] = 1.f / (1.f + __expf(-z));
}

// ---------------- flash attention body (split-kv, normalized bf16 O) ---------
// sbuf carve: Ks = [0,4096), Vts = [4096,8192), Pl = [8192,12288).
// O is stored NORMALIZED per half (O/l) in bf16; combine uses per-half (m,l)
// with weights w_i = l_i*e_i/(l1e1+l2e2): exact regrouping.

__device__ void attn_body(int lin, u16* sbuf,
                          const u16* __restrict__ qb, const u16* __restrict__ kb,
                          const u16* __restrict__ vtb, u16* __restrict__ osmb,
                          float* __restrict__ mlb) {
  u16* Ks = sbuf;
  u16* Vts = sbuf + 4096;
  u16* Pl = sbuf + 8192;
  const int tid = threadIdx.x, lane = tid & 63, w = tid >> 6;
  const int lr = lane & 15, lk = lane >> 4;
  const int bh = lin & 31;
  const int rest = lin >> 5;           // 0..63
  const int qt = 31 - (rest >> 1);     // heavy (large qt) first
  const int half = rest & 1;
  const int hs = (qt + 2) >> 1;        // split point
  const int kt0 = half ? hs : 0;
  const int kt1 = half ? (qt + 1) : hs;

  const u16* kbase0 = kb + (size_t)bh * (L_ * 64);
  const u16* vbase0 = vtb + (size_t)bh * (64 * L_);

  const size_t qbase = ((size_t)bh * L_ + qt * 64 + w * 16 + lr) * 64;
  bf16x8 qfr[2];
  qfr[0] = *(const bf16x8*)(qb + qbase + lk * 8);
  qfr[1] = *(const bf16x8*)(qb + qbase + 32 + lk * 8);

  f32x4 yacc[4];
  float mrow[4], lrow[4];
#pragma unroll
  for (int i = 0; i < 4; ++i) {
    yacc[i] = (f32x4){0.f, 0.f, 0.f, 0.f};
    mrow[i] = -1e30f;
    lrow[i] = 0.f;
  }

  for (int kt = kt0; kt < kt1; ++kt) {
    const int kv0 = kt * 64;
    __syncthreads();
#pragma unroll
    for (int it = 0; it < 2; ++it) {
      int idx = it * 256 + tid;          // 512 x 16B chunks
      int row = idx >> 3, ch = idx & 7;
      int sch = (ch ^ (row & 7)) * 8;
      *(int4*)&Ks[row * 64 + sch] =
          *(const int4*)(kbase0 + (size_t)(kv0 + row) * 64 + ch * 8);
      *(int4*)&Vts[row * 64 + sch] =
          *(const int4*)(vbase0 + (size_t)row * L_ + kv0 + ch * 8);
    }
    __syncthreads();

    f32x4 s[4];
#pragma unroll
    for (int f = 0; f < 4; ++f) {
      f32x4 sf = (f32x4){0.f, 0.f, 0.f, 0.f};
#pragma unroll
      for (int ss = 0; ss < 2; ++ss) {
        bf16x8 kfr = *(const bf16x8*)&Ks[(f * 16 + lr) * 64 +
                                         (((ss * 4 + lk) ^ (lr & 7)) * 8)];
        sf = __builtin_amdgcn_mfma_f32_16x16x32_bf16(qfr[ss], kfr, sf, 0, 0, 0);
      }
      s[f] = sf;
    }
    if (kt == qt) {
#pragma unroll
      for (int f = 0; f < 4; ++f)
#pragma unroll
        for (int rr = 0; rr < 4; ++rr)
          if (f * 16 + lr > w * 16 + lk * 4 + rr) s[f][rr] = -1e30f;
    }
    float mx[4];
#pragma unroll
    for (int rr = 0; rr < 4; ++rr) {
      float m = fmaxf(fmaxf(s[0][rr], s[1][rr]), fmaxf(s[2][rr], s[3][rr]));
      m = fmaxf(m, dpp_mov<0x128>(m));
      m = fmaxf(m, dpp_mov<0x124>(m));
      m = fmaxf(m, dpp_mov<0x122>(m));
      m = fmaxf(m, dpp_mov<0x121>(m));
      mx[rr] = m;
    }
    bool need = (mx[0] > mrow[0] + 8.f) | (mx[1] > mrow[1] + 8.f) |
                (mx[2] > mrow[2] + 8.f) | (mx[3] > mrow[3] + 8.f);
    if (__any(need)) {
#pragma unroll
      for (int rr = 0; rr < 4; ++rr) {
        float mn = fmaxf(mrow[rr], mx[rr]);
        float c = __expf(mrow[rr] - mn);
        lrow[rr] *= c;
#pragma unroll
        for (int nf = 0; nf < 4; ++nf) yacc[nf][rr] *= c;
        mrow[rr] = mn;
      }
    }
    u16* pw = Pl + w * 1024;
#pragma unroll
    for (int rr = 0; rr < 4; ++rr) {
      const int prow = lk * 4 + rr;
      float rs = 0.f;
#pragma unroll
      for (int f = 0; f < 4; ++f) {
        float pv = __expf(s[f][rr] - mrow[rr]);
        rs += pv;
        int chunk = f * 2 + (lr >> 3);
        pw[prow * 64 + ((chunk ^ (prow & 7)) * 8) + (lr & 7)] = f2bf(pv);
      }
      rs = rs + dpp_mov<0x128>(rs);
      rs = rs + dpp_mov<0x124>(rs);
      rs = rs + dpp_mov<0x122>(rs);
      rs = rs + dpp_mov<0x121>(rs);
      lrow[rr] += rs;
    }
#pragma unroll
    for (int s2 = 0; s2 < 2; ++s2) {
      bf16x8 pa = *(const bf16x8*)&pw[lr * 64 + (((s2 * 4 + lk) ^ (lr & 7)) * 8)];
#pragma unroll
      for (int nf = 0; nf < 4; ++nf) {
        bf16x8 vfr = *(const bf16x8*)&Vts[(nf * 16 + lr) * 64 +
                                          (((s2 * 4 + lk) ^ (lr & 7)) * 8)];
        yacc[nf] = __builtin_amdgcn_mfma_f32_16x16x32_bf16(pa, vfr, yacc[nf], 0, 0, 0);
      }
    }
  }

  // store NORMALIZED O (bf16) + per-row (m,l). Empty half: l=0 -> store 0;
  // its combine weight l*e is 0, so the value never contributes.
  float invl[4];
#pragma unroll
  for (int rr = 0; rr < 4; ++rr)
    invl[rr] = lrow[rr] > 0.f ? 1.f / lrow[rr] : 0.f;
  u16* obase = osmb + (size_t)half * 4194304;
#pragma unroll
  for (int nf = 0; nf < 4; ++nf)
#pragma unroll
    for (int rr = 0; rr < 4; ++rr) {
      int rowl = w * 16 + lk * 4 + rr;
      int col = nf * 16 + lr;
      obase[((size_t)bh * L_ + qt * 64 + rowl) * 64 + col] =
          f2bf(yacc[nf][rr] * invl[rr]);
    }
  if (lr == 0) {
    const int rbase = bh * L_ + qt * 64 + w * 16 + lk * 4;
#pragma unroll
    for (int rr = 0; rr < 4; ++rr) {
      mlb[half * 131072 + rbase + rr] = mrow[rr];
      mlb[half * 131072 + 65536 + rbase + rr] = lrow[rr];
    }
  }
}

// ---------------- STP pass1 body (Klds = sbuf[0,4096)) -----------------------

__device__ void stp1_body(int bid, u16* Klds,
                          const u16* __restrict__ kb, const u16* __restrict__ vtb,
                          const float* __restrict__ retb,
                          const float* __restrict__ gamb,
                          float* __restrict__ slocal) {
  const int tid = threadIdx.x, lane = tid & 63, w = tid >> 6;
  const int bh = bid >> 5, c = bid & 31;
  const int hh = bh & 15;
  const int m = lane >> 4, j4 = (lane & 15) * 4;
  const int i0m = w * 16 + m * 4;

  const u16* kcb = kb + ((size_t)bh * L_ + c * 64) * 64;
  GLDS16(&Klds[tid * 8], kcb + tid * 8);
  GLDS16(&Klds[2048 + tid * 8], kcb + 2048 + tid * 8);
  __syncthreads();

  const int hij = (hh * 64 + i0m) * 64 + j4;
  const float4 r0 = *(const float4*)(retb + hij);
  const float4 r1 = *(const float4*)(retb + hij + 64);
  const float4 r2 = *(const float4*)(retb + hij + 128);
  const float4 r3 = *(const float4*)(retb + hij + 192);
  const float4 g0 = *(const float4*)(gamb + hij);
  const float4 g1 = *(const float4*)(gamb + hij + 64);
  const float4 g2 = *(const float4*)(gamb + hij + 128);
  const float4 g3 = *(const float4*)(gamb + hij + 192);
  const u16* vbp = vtb + ((size_t)bh * 64 + i0m) * L_ + c * 64;

  float4 s0 = {0,0,0,0}, s1 = {0,0,0,0}, s2 = {0,0,0,0}, s3 = {0,0,0,0};
#pragma unroll 1
  for (int t8 = 0; t8 < 8; ++t8) {
    const bf16x8 va = *(const bf16x8*)(vbp + t8 * 8);
    const bf16x8 vb = *(const bf16x8*)(vbp + L_ + t8 * 8);
    const bf16x8 vc = *(const bf16x8*)(vbp + 2 * L_ + t8 * 8);
    const bf16x8 vd = *(const bf16x8*)(vbp + 3 * L_ + t8 * 8);
#pragma unroll
    for (int tt = 0; tt < 8; ++tt) {
      const ushort4 k4u = *(const ushort4*)&Klds[(t8 * 8 + tt) * 64 + j4];
      const float kx = bf2f(k4u.x), ky = bf2f(k4u.y),
                  kz = bf2f(k4u.z), kw = bf2f(k4u.w);
      stp_upd1(s0, r0, g0, bf2f((u16)va[tt]), kx, ky, kz, kw);
      stp_upd1(s1, r1, g1, bf2f((u16)vb[tt]), kx, ky, kz, kw);
      stp_upd1(s2, r2, g2, bf2f((u16)vc[tt]), kx, ky, kz, kw);
      stp_upd1(s3, r3, g3, bf2f((u16)vd[tt]), kx, ky, kz, kw);
    }
  }
  float* sb = slocal + (((size_t)(bh * 32 + c) * 64) + i0m) * 64 + j4;
  *(float4*)(sb)       = s0;
  *(float4*)(sb + 64)  = s1;
  *(float4*)(sb + 128) = s2;
  *(float4*)(sb + 192) = s3;
}

// fused: attn split-kv (2048 blocks) + stp_pass1 (1024 blocks).
__global__ __launch_bounds__(256, 2) void attn_stp1_kernel(
    const u16* __restrict__ qb, const u16* __restrict__ kb,
    const u16* __restrict__ vtb, u16* __restrict__ osmb,
    float* __restrict__ mlb, const float* __restrict__ retb,
    const float* __restrict__ gamb, float* __restrict__ slocal) {
  __shared__ u16 sbuf[12288];  // 24KB union
  const int bid = blockIdx.x;
  if (bid < 2048) attn_body(bid, sbuf, qb, kb, vtb, osmb, mlb);
  else            stp1_body(bid - 2048, sbuf, kb, vtb, retb, gamb, slocal);
}

// Boundary scan: sequential over 32 chunks, parallel over (bh,i,j).
__global__ __launch_bounds__(256) void stp_scan(
    const float* __restrict__ retb64, float* __restrict__ slocal) {
  const int idx = blockIdx.x * 256 + threadIdx.x;  // 0..131071 = (bh,i,j)
  const int j = idx & 63, i1 = (idx >> 6) & 63, bh = idx >> 12;
  const int hh = bh & 15;
  const float r64 = retb64[(hh * 64 + i1) * 64 + j];
  float carry = 0.f;
  for (int c = 0; c < 32; ++c) {
    const size_t off = ((((size_t)bh * 32 + c) * 64 + i1) * 64 + j);
    const float sl = slocal[off];
    slocal[off] = carry;
    carry = fmaf(r64, carry, sl);
  }
}

// Pass 2 + FUSED BLEND (LDS-staged): the t-loop writes y_stp to LDS, then one
// barrier and a block-wide COALESCED epilogue does the split-kv combine (bf16
// normalized O, f32 weights) + gate and writes ycomb bf16.
__global__ __launch_bounds__(256, 4) void stp_pass2(
    const u16* __restrict__ qb, const u16* __restrict__ kb,
    const u16* __restrict__ vtb, const float* __restrict__ retb,
    const float* __restrict__ gamb, const float* __restrict__ wst,
    const float* __restrict__ slocal, const u16* __restrict__ osmb,
    const float* __restrict__ mlb, const float* __restrict__ alp,
    u16* __restrict__ ycomb) {
  __shared__ u16 KQ[8192];         // [0..4095] K, [4096..8191] Q
  __shared__ float ylds[4096];     // [t][dim] 64x64 f32 y_stp stage
  const int tid = threadIdx.x, lane = tid & 63, w = tid >> 6;
  const int bh = blockIdx.x >> 5, c = blockIdx.x & 31;
  const int hh = bh & 15;
  const int bb = bh >> 4;
  const int m = lane >> 4, jc = lane & 15, j4 = jc * 4;
  const int i0m = w * 16 + m * 4;

  const size_t cb = ((size_t)bh * L_ + c * 64) * 64;
  GLDS16(&KQ[tid * 8], kb + cb + tid * 8);
  GLDS16(&KQ[2048 + tid * 8], kb + cb + 2048 + tid * 8);
  GLDS16(&KQ[4096 + tid * 8], qb + cb + tid * 8);
  GLDS16(&KQ[6144 + tid * 8], qb + cb + 2048 + tid * 8);
  __syncthreads();

  const int hij = (hh * 64 + i0m) * 64 + j4;
  const float4 r0 = *(const float4*)(retb + hij);
  const float4 r1 = *(const float4*)(retb + hij + 64);
  const float4 r2 = *(const float4*)(retb + hij + 128);
  const float4 r3 = *(const float4*)(retb + hij + 192);
  const float4 g0 = *(const float4*)(gamb + hij);
  const float4 g1 = *(const float4*)(gamb + hij + 64);
  const float4 g2 = *(const float4*)(gamb + hij + 128);
  const float4 g3 = *(const float4*)(gamb + hij + 192);
  const float4 w0 = *(const float4*)(wst + hij);
  const float4 w1 = *(const float4*)(wst + hij + 64);
  const float4 w2 = *(const float4*)(wst + hij + 128);
  const float4 w3 = *(const float4*)(wst + hij + 192);

  const float* sb = slocal + (((size_t)(bh * 32 + c) * 64) + i0m) * 64 + j4;
  float4 z0 = *(const float4*)(sb);
  float4 z1 = *(const float4*)(sb + 64);
  float4 z2 = *(const float4*)(sb + 128);
  float4 z3 = *(const float4*)(sb + 192);

  float4 wlc0, wlc1, wlc2, wlc3;
  wlc0.x = w0.x * (1.f - r0.x); wlc0.y = w0.y * (1.f - r0.y);
  wlc0.z = w0.z * (1.f - r0.z); wlc0.w = w0.w * (1.f - r0.w);
  wlc1.x = w1.x * (1.f - r1.x); wlc1.y = w1.y * (1.f - r1.y);
  wlc1.z = w1.z * (1.f - r1.z); wlc1.w = w1.w * (1.f - r1.w);
  wlc2.x = w2.x * (1.f - r2.x); wlc2.y = w2.y * (1.f - r2.y);
  wlc2.z = w2.z * (1.f - r2.z); wlc2.w = w2.w * (1.f - r2.w);
  wlc3.x = w3.x * (1.f - r3.x); wlc3.y = w3.y * (1.f - r3.y);
  wlc3.z = w3.z * (1.f - r3.z); wlc3.w = w3.w * (1.f - r3.w);
  z0.x += w0.x; z0.y += w0.y; z0.z += w0.z; z0.w += w0.w;
  z1.x += w1.x; z1.y += w1.y; z1.z += w1.z; z1.w += w1.w;
  z2.x += w2.x; z2.y += w2.y; z2.z += w2.z; z2.w += w2.w;
  z3.x += w3.x; z3.y += w3.y; z3.z += w3.z; z3.w += w3.w;

  const u16* vbp = vtb + ((size_t)bh * 64 + i0m) * L_ + c * 64;

#pragma unroll 1
  for (int t8 = 0; t8 < 8; ++t8) {
    const bf16x8 va = *(const bf16x8*)(vbp + t8 * 8);
    const bf16x8 vb = *(const bf16x8*)(vbp + L_ + t8 * 8);
    const bf16x8 vc = *(const bf16x8*)(vbp + 2 * L_ + t8 * 8);
    const bf16x8 vd = *(const bf16x8*)(vbp + 3 * L_ + t8 * 8);
#pragma unroll
    for (int tt = 0; tt < 8; ++tt) {
      const int t = t8 * 8 + tt;
      const ushort4 k4u = *(const ushort4*)&KQ[t * 64 + j4];
      const ushort4 q4u = *(const ushort4*)&KQ[4096 + t * 64 + j4];
      const float kx = bf2f(k4u.x), ky = bf2f(k4u.y),
                  kz = bf2f(k4u.z), kw = bf2f(k4u.w);
      const float qx = bf2f(q4u.x), qy = bf2f(q4u.y),
                  qz = bf2f(q4u.z), qw = bf2f(q4u.w);
      stp_upd(z0, r0, g0, wlc0, bf2f((u16)va[tt]), kx, ky, kz, kw);
      stp_upd(z1, r1, g1, wlc1, bf2f((u16)vb[tt]), kx, ky, kz, kw);
      stp_upd(z2, r2, g2, wlc2, bf2f((u16)vc[tt]), kx, ky, kz, kw);
      stp_upd(z3, r3, g3, wlc3, bf2f((u16)vd[tt]), kx, ky, kz, kw);
      float p0 = dpp_red16(stp_dot(z0, qx, qy, qz, qw));
      float p1 = dpp_red16(stp_dot(z1, qx, qy, qz, qw));
      float p2 = dpp_red16(stp_dot(z2, qx, qy, qz, qw));
      float p3 = dpp_red16(stp_dot(z3, qx, qy, qz, qw));
      if (jc == 0) {
        float4 yo;  // y_stp = p*8 (undo qb's 0.125, exact pow2)
        yo.x = p0 * 8.f; yo.y = p1 * 8.f; yo.z = p2 * 8.f; yo.w = p3 * 8.f;
        *(float4*)&ylds[t * 64 + i0m] = yo;
      }
    }
  }

  __syncthreads();  // all waves' y_stp strips visible

  // Coalesced blend epilogue: 1024 float4-groups over 256 threads.
#pragma unroll
  for (int k2 = 0; k2 < 4; ++k2) {
    const int gi = k2 * 256 + tid;   // 0..1023
    const int t = gi >> 4;           // token within chunk
    const int d4 = (gi & 15) * 4;    // dim group
    const int ll = c * 64 + t;
    const int rowg = bh * L_ + ll;
    float m1 = mlb[rowg],          l1 = mlb[65536 + rowg];
    float m2 = mlb[131072 + rowg], l2 = mlb[196608 + rowg];
    float mm = fmaxf(m1, m2);
    float e1 = __expf(m1 - mm), e2 = __expf(m2 - mm);
    float inv = 1.f / fmaf(l1, e1, l2 * e2);
    float w1v = l1 * e1 * inv, w2v = l2 * e2 * inv;
    size_t bi = (size_t)rowg * 64 + d4;
    ushort4 o1u = *(const ushort4*)(osmb + bi);
    ushort4 o2u = *(const ushort4*)(osmb + 4194304 + bi);
    const int mtok = bb * L_ + ll;
    float a = alp[mtok * 16 + hh];
    const float na = 1.f - a;
    float4 ys = *(const float4*)&ylds[t * 64 + d4];
    ushort4 oo;
    oo.x = f2bf(a * (w1v * bf2f(o1u.x) + w2v * bf2f(o2u.x)) + na * ys.x);
    oo.y = f2bf(a * (w1v * bf2f(o1u.y) + w2v * bf2f(o2u.y)) + na * ys.y);
    oo.z = f2bf(a * (w1v * bf2f(o1u.z) + w2v * bf2f(o2u.z)) + na * ys.z);
    oo.w = f2bf(a * (w1v * bf2f(o1u.w) + w2v * bf2f(o2u.w)) + na * ys.w);
    *(ushort4*)(ycomb + (size_t)mtok * 1024 + hh * 64 + d4) = oo;
  }
}

// ---------------- launch ----------------

extern "C" void kernel_launch(void* const* d_in, const int* in_sizes, int n_in,
                              void* d_out, int out_size, void* d_ws, size_t ws_size,
                              hipStream_t stream) {
  const float* x       = (const float*)d_in[0];
  const float* wqkv_w  = (const float*)d_in[1];
  const float* wqkv_b  = (const float*)d_in[2];
  const float* out_w   = (const float*)d_in[3];
  const float* out_b   = (const float*)d_in[4];
  const float* w_stat  = (const float*)d_in[5];
  const float* lam     = (const float*)d_in[6];
  const float* gma     = (const float*)d_in[7];
  const float* g_w1    = (const float*)d_in[8];
  const float* g_b1    = (const float*)d_in[9];
  const float* g_w2    = (const float*)d_in[10];
  const float* g_b2    = (const float*)d_in[11];

  char* ws = (char*)d_ws;
  size_t off = 0;
  auto nxt = [&](size_t b) { size_t r = off; off += (b + 255) & ~(size_t)255; return r; };
  u16*   xbf   = (u16*)(ws + nxt((size_t)4096 * 1024 * 2));
  u16*   wqkvT = (u16*)(ws + nxt((size_t)3072 * 1024 * 2));
  u16*   owT   = (u16*)(ws + nxt((size_t)1024 * 1024 * 2));
  u16*   g1T   = (u16*)(ws + nxt((size_t)512 * 1024 * 2));
  u16*   qb    = (u16*)(ws + nxt((size_t)4194304 * 2));
  u16*   kb    = (u16*)(ws + nxt((size_t)4194304 * 2));
  u16*   vtb   = (u16*)(ws + nxt((size_t)4194304 * 2));
  u16*   osmb  = (u16*)(ws + nxt((size_t)2 * 4194304 * 2));   // 2 halves, bf16 O/l
  float* mlb   = (float*)(ws + nxt((size_t)4 * 65536 * 4));   // m/l per half
  // NO aliases: hbuf, ycomb, slocal all private.
  float* hbuf  = (float*)(ws + nxt((size_t)4096 * 512 * 4));   // 8MB
  u16*   ycomb = (u16*)(ws + nxt((size_t)4096 * 1024 * 2));    // 8MB
  float* slocal= (float*)(ws + nxt((size_t)4194304 * 4));      // 16MB
  float* alp   = (float*)(ws + nxt((size_t)4096 * 16 * 4));
  float* retb  = (float*)(ws + nxt((size_t)65536 * 4));
  float* gamb  = (float*)(ws + nxt((size_t)65536 * 4));
  float* retb64= (float*)(ws + nxt((size_t)65536 * 4));

  dim3 blk(256);
  prep_fused<<<8960, blk, 0, stream>>>(x, xbf, wqkv_w, wqkvT, out_w, owT,
                                       g_w1, g1T, lam, gma, retb, gamb, retb64);

  GemmP p0 = {xbf, wqkvT, 4096, 3072, 1024, wqkv_b,
              qb, kb, vtb, nullptr, nullptr};
  GemmP p1 = {xbf, g1T, 4096, 512, 1024, g_b1,
              nullptr, nullptr, nullptr, hbuf, nullptr};
  gemm01_kernel<<<896, blk, 0, stream>>>(p0, p1);

  alpha_kernel<<<256, blk, 0, stream>>>(hbuf, g_w2, g_b2, alp);

  // attn split-kv (2048) + stp_pass1 (1024)
  attn_stp1_kernel<<<3072, blk, 0, stream>>>(qb, kb, vtb, osmb, mlb,
                                             retb, gamb, slocal);

  stp_scan<<<512, blk, 0, stream>>>(retb64, slocal);

  // pass2 with LDS-staged fused blend: writes ycomb directly.
  stp_pass2<<<1024, blk, 0, stream>>>(qb, kb, vtb, retb, gamb, w_stat,
                                      slocal, osmb, mlb, alp, ycomb);

  GemmP p2 = {ycomb, owT, 4096, 1024, 1024, out_b,
              nullptr, nullptr, nullptr, nullptr, (float*)d_out};
  gemm2_kernel<<<dim3(8, 32), blk, 0, stream>>>(p2);
}

// Round 24
// 227.316 us; speedup vs baseline: 1.0206x; 1.0206x over previous
//
#include <hip/hip_runtime.h>
#include <cstdint>
#include <cstddef>

#define B_ 2
#define L_ 2048
#define D_ 1024
#define H_ 16
#define DH 64

typedef __attribute__((ext_vector_type(8))) short bf16x8;
typedef __attribute__((ext_vector_type(4))) float f32x4;
typedef unsigned short u16;

__device__ inline u16 f2bf(float f) {
  unsigned u = __builtin_bit_cast(unsigned, f);
  u += 0x7fffu + ((u >> 16) & 1u);
  return (u16)(u >> 16);
}

__device__ inline float bf2f(u16 x) {
  return __builtin_bit_cast(float, (unsigned)x << 16);
}

// DPP lane-move (VALU pipe). Returns src shuffled per CTRL; full masks.
template <int CTRL>
__device__ inline float dpp_mov(float x) {
  int t = __builtin_amdgcn_update_dpp(0, __builtin_bit_cast(int, x), CTRL, 0xf, 0xf, true);
  return __builtin_bit_cast(float, t);
}

// global -> LDS direct (16B per lane). Staging layout must be linear in lane.
#define GLDS16(ldst, gsrc)                                              \
  __builtin_amdgcn_global_load_lds(                                    \
      (const __attribute__((address_space(1))) void*)(gsrc),           \
      (__attribute__((address_space(3))) void*)(ldst), 16, 0, 0)

// STP row helpers
__device__ inline void stp_upd(float4& z, const float4 r, const float4 g,
                               const float4 wlc, float vv,
                               float kx, float ky, float kz, float kw) {
  z.x = fmaf(r.x, z.x, fmaf(g.x * vv, kx, wlc.x));
  z.y = fmaf(r.y, z.y, fmaf(g.y * vv, ky, wlc.y));
  z.z = fmaf(r.z, z.z, fmaf(g.z * vv, kz, wlc.z));
  z.w = fmaf(r.w, z.w, fmaf(g.w * vv, kw, wlc.w));
}

__device__ inline void stp_upd1(float4& z, const float4 r, const float4 g,
                                float vv, float kx, float ky, float kz, float kw) {
  z.x = fmaf(r.x, z.x, (g.x * vv) * kx);
  z.y = fmaf(r.y, z.y, (g.y * vv) * ky);
  z.z = fmaf(r.z, z.z, (g.z * vv) * kz);
  z.w = fmaf(r.w, z.w, (g.w * vv) * kw);
}

__device__ inline float stp_dot(const float4 z, float qx, float qy, float qz, float qw) {
  float p = z.x * qx;
  p = fmaf(z.y, qy, p);
  p = fmaf(z.z, qz, p);
  p = fmaf(z.w, qw, p);
  return p;
}

__device__ inline float dpp_red16(float p) {
  p = p + dpp_mov<0x128>(p);  // row_ror:8 (16-lane closure)
  p = p + dpp_mov<0x124>(p);
  p = p + dpp_mov<0x122>(p);
  p = p + dpp_mov<0x121>(p);
  return p;
}

// ---------------- fused prep kernel (block-range dispatch) ----------------

__device__ inline void d_transpose(const float* __restrict__ in,
                                   u16* __restrict__ out, int R, int C,
                                   int bx, int by, float tile[32][33], int tid) {
  const int tx = tid & 31, ty = tid >> 5;
  const int c0 = bx * 32, r0 = by * 32;
#pragma unroll
  for (int j = 0; j < 4; ++j)
    tile[ty + j * 8][tx] = in[(size_t)(r0 + ty + j * 8) * C + c0 + tx];
  __syncthreads();
#pragma unroll
  for (int j = 0; j < 4; ++j)
    out[(size_t)(c0 + ty + j * 8) * R + r0 + tx] = f2bf(tile[tx][ty + j * 8]);
}

__global__ __launch_bounds__(256) void prep_fused(
    const float* __restrict__ x, u16* __restrict__ xbf,
    const float* __restrict__ wqkv_w, u16* __restrict__ wqkvT,
    const float* __restrict__ out_w, u16* __restrict__ owT,
    const float* __restrict__ g_w1, u16* __restrict__ g1T,
    const float* __restrict__ lam, const float* __restrict__ gma,
    float* __restrict__ retb, float* __restrict__ gamb,
    float* __restrict__ retb64) {
  __shared__ float tile[32][33];
  const int bid = blockIdx.x, tid = threadIdx.x;
  if (bid < 4096) {
    int i = bid * 256 + tid;
    float4 v = ((const float4*)x)[i];
    ushort4 o;
    o.x = f2bf(v.x); o.y = f2bf(v.y); o.z = f2bf(v.z); o.w = f2bf(v.w);
    ((ushort4*)xbf)[i] = o;
  } else if (bid < 7168) {
    int r = bid - 4096;
    d_transpose(wqkv_w, wqkvT, 1024, 3072, r % 96, r / 96, tile, tid);
  } else if (bid < 8192) {
    int r = bid - 7168;
    d_transpose(out_w, owT, 1024, 1024, r % 32, r / 32, tile, tid);
  } else if (bid < 8704) {
    int r = bid - 8192;
    d_transpose(g_w1, g1T, 1024, 512, r % 16, r / 16, tile, tid);
  } else {
    int i = (bid - 8704) * 256 + tid;  // 65536 total
    float l = lam[i];
    float r = 1.f / (1.f + expf(l));   // 1 - sigmoid(l)
    retb[i] = r;
    gamb[i] = gma[i] * 0.125f;         // fold k-scale into Gamma
    float r2 = r * r;                   // r^64 by 6 squarings
    float r4 = r2 * r2;
    float r8 = r4 * r4;
    float r16 = r8 * r8;
    float r32 = r16 * r16;
    retb64[i] = r32 * r32;
  }
}

// ---------------- GEMM body (C = A @ Bt^T), A: MxK bf16, Bt: NxK bf16 --------
// BK=64, chunk-swizzle (rule 21c), tileT aliases As/Bs for EPI0's v-epilogue.

struct GemmP {
  const u16* A; const u16* Bt; int M, N, K;
  const float* bias;
  u16* qb; u16* kb; u16* vtb;  // EPI 0
  float* hout;                 // EPI 1
  float* outp;                 // EPI 2
};

template <int EPI>
__device__ void gemm_body(const GemmP& p, int lin0, int nwgx, int nwgtot,
                          u16* As, u16* Bs, u16* tileT) {
  const int tid = threadIdx.x;
  const int lane = tid & 63;
  const int w = tid >> 6;
  const int wr = w >> 1, wc = w & 1;
  const int lr = lane & 15, lk = lane >> 4;
  const int cpx = nwgtot >> 3;
  const int lin = (lin0 & 7) * cpx + (lin0 >> 3);
  const int m0 = (lin / nwgx) * 128, n0 = (lin % nwgx) * 128;

  f32x4 acc[4][4];
#pragma unroll
  for (int i = 0; i < 4; ++i)
#pragma unroll
    for (int j = 0; j < 4; ++j) acc[i][j] = (f32x4){0.f, 0.f, 0.f, 0.f};

  for (int k0 = 0; k0 < p.K; k0 += 64) {
    __syncthreads();
#pragma unroll
    for (int it = 0; it < 4; ++it) {
      int idx = it * 256 + tid;               // 0..1023 chunk slots
      int row = idx >> 3;
      int ch = (idx & 7) ^ (row & 7);         // inverse-swizzled source chunk
      GLDS16(&As[idx * 8], p.A + (size_t)(m0 + row) * p.K + k0 + ch * 8);
      GLDS16(&Bs[idx * 8], p.Bt + (size_t)(n0 + row) * p.K + k0 + ch * 8);
    }
    __syncthreads();
#pragma unroll
    for (int kk = 0; kk < 2; ++kk) {
      const int slot = ((kk * 4 + lk) ^ (lr & 7)) * 8;
      bf16x8 af[4], bfr[4];
#pragma unroll
      for (int mr = 0; mr < 4; ++mr)
        af[mr] = *(const bf16x8*)&As[(wr * 64 + mr * 16 + lr) * 64 + slot];
#pragma unroll
      for (int nr = 0; nr < 4; ++nr)
        bfr[nr] = *(const bf16x8*)&Bs[(wc * 64 + nr * 16 + lr) * 64 + slot];
#pragma unroll
      for (int mr = 0; mr < 4; ++mr)
#pragma unroll
        for (int nr = 0; nr < 4; ++nr)
          acc[mr][nr] = __builtin_amdgcn_mfma_f32_16x16x32_bf16(af[mr], bfr[nr], acc[mr][nr], 0, 0, 0);
    }
  }

  if constexpr (EPI == 0) {
    if (n0 < 2048) {
#pragma unroll
      for (int mr = 0; mr < 4; ++mr)
#pragma unroll
        for (int nr = 0; nr < 4; ++nr) {
          const int col = n0 + wc * 64 + nr * 16 + lr;
#pragma unroll
          for (int rr = 0; rr < 4; ++rr) {
            const int row = m0 + wr * 64 + mr * 16 + lk * 4 + rr;
            float v = acc[mr][nr][rr] + p.bias[col];
            int which = col >> 10, hh = (col >> 6) & 15, ii = col & 63;
            int b = row >> 11, ll = row & 2047;
            size_t bi = ((size_t)(b * 16 + hh) * L_ + ll) * 64 + ii;
            if (which == 0) p.qb[bi] = f2bf(v * 0.125f);
            else            p.kb[bi] = f2bf(v);
          }
        }
    } else {
      // v region: two-pass LDS transpose in tileT (aliases As/Bs).
#pragma unroll 1
      for (int h2 = 0; h2 < 2; ++h2) {
        __syncthreads();
        if (wr == h2) {
#pragma unroll
          for (int mr = 0; mr < 4; ++mr)
#pragma unroll
            for (int nr = 0; nr < 4; ++nr) {
              const int cl = wc * 64 + nr * 16 + lr;
              const float bv = p.bias[n0 + cl];
#pragma unroll
              for (int rr = 0; rr < 4; ++rr) {
                const int rl2 = mr * 16 + lk * 4 + rr;  // 0..63
                tileT[cl * 72 + rl2] = f2bf(acc[mr][nr][rr] + bv);
              }
            }
        }
        __syncthreads();
        const int c = tid >> 1, half = tid & 1;
        const int vcol = (n0 - 2048) + c;
        const int hh = vcol >> 6, ii = vcol & 63;
        const int b = m0 >> 11;
        const int ll0 = (m0 & 2047) + h2 * 64 + half * 32;
        u16* dst = p.vtb + ((size_t)(b * 16 + hh) * 64 + ii) * L_ + ll0;
        const u16* src = &tileT[c * 72 + half * 32];
#pragma unroll
        for (int k = 0; k < 4; ++k)
          *(int4*)(dst + k * 8) = *(const int4*)(src + k * 8);
      }
    }
  } else {
#pragma unroll
    for (int mr = 0; mr < 4; ++mr)
#pragma unroll
      for (int nr = 0; nr < 4; ++nr) {
        const int col = n0 + wc * 64 + nr * 16 + lr;
#pragma unroll
        for (int rr = 0; rr < 4; ++rr) {
          const int row = m0 + wr * 64 + mr * 16 + lk * 4 + rr;
          float v = acc[mr][nr][rr] + p.bias[col];
          if constexpr (EPI == 1) {
            float g = 0.5f * v * (1.f + erff(v * 0.70710678118f));  // exact gelu
            p.hout[(size_t)row * p.N + col] = g;
          } else {
            p.outp[(size_t)row * p.N + col] = v;
          }
        }
      }
  }
}

// fused gemm<0> (768 blocks) + gemm<1> (128 blocks)
__global__ __launch_bounds__(256, 4) void gemm01_kernel(GemmP p0, GemmP p1) {
  __shared__ u16 sbuf[16384];
  u16* As = sbuf;
  u16* Bs = sbuf + 8192;
  u16* tileT = sbuf;
  const int bid = blockIdx.x;
  if (bid < 768) gemm_body<0>(p0, bid, 24, 768, As, Bs, tileT);
  else           gemm_body<1>(p1, bid - 768, 4, 128, As, Bs, tileT);
}

// standalone gemm<2> (out proj)
__global__ __launch_bounds__(256, 4) void gemm2_kernel(GemmP p) {
  __shared__ u16 As[8192];
  __shared__ u16 Bs[8192];
  const int lin0 = (int)blockIdx.x + 8 * (int)blockIdx.y;
  gemm_body<2>(p, lin0, 8, 256, As, Bs, nullptr);
}

// ---------------- gate alpha: sigmoid(h @ w2 + b2) ----------------

__global__ __launch_bounds__(256) void alpha_kernel(
    const float* __restrict__ hbuf, const float* __restrict__ w2,
    const float* __restrict__ b2, float* __restrict__ alp) {
  const int tid = threadIdx.x;
  const int row = blockIdx.x * 16 + (tid >> 4);
  const int n = tid & 15;
  const float4* h4 = (const float4*)(hbuf + (size_t)row * 512);
  float acc = 0.f;
#pragma unroll 2
  for (int kk = 0; kk < 128; ++kk) {
    float4 hv = h4[kk];
    acc = fmaf(hv.x, w2[(kk * 4 + 0) * 16 + n], acc);
    acc = fmaf(hv.y, w2[(kk * 4 + 1) * 16 + n], acc);
    acc = fmaf(hv.z, w2[(kk * 4 + 2) * 16 + n], acc);
    acc = fmaf(hv.w, w2[(kk * 4 + 3) * 16 + n], acc);
  }
  float z = acc + b2[n];
  alp[row * 16 + n] = 1.f / (1.f + __expf(-z));
}

// ---------------- flash attention body (split-kv, KVBLK=128, bf16 O) ---------
// sbuf carve: Ks = [0,8192) [128][64], Vts = [8192,16384) [64][128],
// Pl = [16384,24576) [4][16][128]. All XOR-swizzled (R9-verified 128-wide
// forms). Halves split the 128-tile range; only the LAST tile masks
// (global col > row covers ragged edges).

__device__ void attn_body(int lin, u16* sbuf,
                          const u16* __restrict__ qb, const u16* __restrict__ kb,
                          const u16* __restrict__ vtb, u16* __restrict__ osmb,
                          float* __restrict__ mlb) {
  u16* Ks = sbuf;
  u16* Vts = sbuf + 8192;
  u16* Pl = sbuf + 16384;
  const int tid = threadIdx.x, lane = tid & 63, w = tid >> 6;
  const int lr = lane & 15, lk = lane >> 4;
  const int bh = lin & 31;
  const int rest = lin >> 5;           // 0..63
  const int qt = 31 - (rest >> 1);     // heavy (large qt) first
  const int half = rest & 1;
  const int ktot = (qt >> 1) + 1;      // 128-tiles covering [0, (qt+1)*64)
  const int hs = (ktot + 1) >> 1;      // split point
  const int kt0 = half ? hs : 0;
  const int kt1 = half ? ktot : hs;

  const u16* kbase0 = kb + (size_t)bh * (L_ * 64);
  const u16* vbase0 = vtb + (size_t)bh * (64 * L_);

  const size_t qbase = ((size_t)bh * L_ + qt * 64 + w * 16 + lr) * 64;
  bf16x8 qfr[2];
  qfr[0] = *(const bf16x8*)(qb + qbase + lk * 8);
  qfr[1] = *(const bf16x8*)(qb + qbase + 32 + lk * 8);

  f32x4 yacc[4];
  float mrow[4], lrow[4];
#pragma unroll
  for (int i = 0; i < 4; ++i) {
    yacc[i] = (f32x4){0.f, 0.f, 0.f, 0.f};
    mrow[i] = -1e30f;
    lrow[i] = 0.f;
  }

  for (int kt = kt0; kt < kt1; ++kt) {
    const int kv0 = kt * 128;
    __syncthreads();
#pragma unroll
    for (int it = 0; it < 4; ++it) {
      int idx = it * 256 + tid;            // 0..1023
      int krow = idx >> 3, kch = idx & 7;  // K: 128 rows x 8 chunks
      *(int4*)&Ks[krow * 64 + ((kch ^ (krow & 7)) * 8)] =
          *(const int4*)(kbase0 + (size_t)(kv0 + krow) * 64 + kch * 8);
      int vrow = idx >> 4, vch = idx & 15; // Vt: 64 rows x 16 chunks
      *(int4*)&Vts[vrow * 128 + ((vch ^ (vrow & 15)) * 8)] =
          *(const int4*)(vbase0 + (size_t)vrow * L_ + kv0 + vch * 8);
    }
    __syncthreads();

    // QK^T: s[f] covers kv cols kv0 + f*16+lr
    f32x4 s[8];
#pragma unroll
    for (int f = 0; f < 8; ++f) {
      f32x4 sf = (f32x4){0.f, 0.f, 0.f, 0.f};
#pragma unroll
      for (int ss = 0; ss < 2; ++ss) {
        bf16x8 kfr = *(const bf16x8*)&Ks[(f * 16 + lr) * 64 +
                                         (((ss * 4 + lk) ^ (lr & 7)) * 8)];
        sf = __builtin_amdgcn_mfma_f32_16x16x32_bf16(qfr[ss], kfr, sf, 0, 0, 0);
      }
      s[f] = sf;
    }
    if (kt == ktot - 1) {  // last tile: mask global col > row
      const int rowg0 = qt * 64 + w * 16 + lk * 4;
#pragma unroll
      for (int f = 0; f < 8; ++f) {
        const int colg = kv0 + f * 16 + lr;
#pragma unroll
        for (int rr = 0; rr < 4; ++rr)
          if (colg > rowg0 + rr) s[f][rr] = -1e30f;
      }
    }
    // tile max per row (16-lane DPP closure)
    float mx[4];
#pragma unroll
    for (int rr = 0; rr < 4; ++rr) {
      float m = s[0][rr];
#pragma unroll
      for (int f = 1; f < 8; ++f) m = fmaxf(m, s[f][rr]);
      m = fmaxf(m, dpp_mov<0x128>(m));
      m = fmaxf(m, dpp_mov<0x124>(m));
      m = fmaxf(m, dpp_mov<0x122>(m));
      m = fmaxf(m, dpp_mov<0x121>(m));
      mx[rr] = m;
    }
    // defer-max (T13): skip rescale unless a row grew by > 8 (exact skip).
    bool need = (mx[0] > mrow[0] + 8.f) | (mx[1] > mrow[1] + 8.f) |
                (mx[2] > mrow[2] + 8.f) | (mx[3] > mrow[3] + 8.f);
    if (__any(need)) {
#pragma unroll
      for (int rr = 0; rr < 4; ++rr) {
        float mn = fmaxf(mrow[rr], mx[rr]);
        float c = __expf(mrow[rr] - mn);
        lrow[rr] *= c;
#pragma unroll
        for (int nf = 0; nf < 4; ++nf) yacc[nf][rr] *= c;
        mrow[rr] = mn;
      }
    }
    // exp fused with P-store (swizzled, 16-chunk rows); row-sum via DPP.
    u16* pw = Pl + w * 2048;
#pragma unroll
    for (int rr = 0; rr < 4; ++rr) {
      const int prow = lk * 4 + rr;
      float rs = 0.f;
#pragma unroll
      for (int f = 0; f < 8; ++f) {
        float pv = __expf(s[f][rr] - mrow[rr]);
        rs += pv;
        int chunk = f * 2 + (lr >> 3);
        pw[prow * 128 + ((chunk ^ prow) * 8) + (lr & 7)] = f2bf(pv);
      }
      rs = rs + dpp_mov<0x128>(rs);
      rs = rs + dpp_mov<0x124>(rs);
      rs = rs + dpp_mov<0x122>(rs);
      rs = rs + dpp_mov<0x121>(rs);
      lrow[rr] += rs;
    }
    // PV: yacc[nf] += P[16 x 128] * Vt[d rows][128 kv]
#pragma unroll
    for (int s2 = 0; s2 < 4; ++s2) {
      bf16x8 pa = *(const bf16x8*)&pw[lr * 128 + (((s2 * 4 + lk) ^ lr) * 8)];
#pragma unroll
      for (int nf = 0; nf < 4; ++nf) {
        bf16x8 vfr = *(const bf16x8*)&Vts[(nf * 16 + lr) * 128 +
                                          (((s2 * 4 + lk) ^ lr) * 8)];
        yacc[nf] = __builtin_amdgcn_mfma_f32_16x16x32_bf16(pa, vfr, yacc[nf], 0, 0, 0);
      }
    }
  }

  // store NORMALIZED O (bf16) + per-row (m,l). Empty half: l=0 -> store 0;
  // its combine weight l*e is 0, so the value never contributes.
  float invl[4];
#pragma unroll
  for (int rr = 0; rr < 4; ++rr)
    invl[rr] = lrow[rr] > 0.f ? 1.f / lrow[rr] : 0.f;
  u16* obase = osmb + (size_t)half * 4194304;
#pragma unroll
  for (int nf = 0; nf < 4; ++nf)
#pragma unroll
    for (int rr = 0; rr < 4; ++rr) {
      int rowl = w * 16 + lk * 4 + rr;
      int col = nf * 16 + lr;
      obase[((size_t)bh * L_ + qt * 64 + rowl) * 64 + col] =
          f2bf(yacc[nf][rr] * invl[rr]);
    }
  if (lr == 0) {
    const int rbase = bh * L_ + qt * 64 + w * 16 + lk * 4;
#pragma unroll
    for (int rr = 0; rr < 4; ++rr) {
      mlb[half * 131072 + rbase + rr] = mrow[rr];
      mlb[half * 131072 + 65536 + rbase + rr] = lrow[rr];
    }
  }
}

// ---------------- STP pass1 body (Klds = sbuf[0,4096)) -----------------------

__device__ void stp1_body(int bid, u16* Klds,
                          const u16* __restrict__ kb, const u16* __restrict__ vtb,
                          const float* __restrict__ retb,
                          const float* __restrict__ gamb,
                          float* __restrict__ slocal) {
  const int tid = threadIdx.x, lane = tid & 63, w = tid >> 6;
  const int bh = bid >> 5, c = bid & 31;
  const int hh = bh & 15;
  const int m = lane >> 4, j4 = (lane & 15) * 4;
  const int i0m = w * 16 + m * 4;

  const u16* kcb = kb + ((size_t)bh * L_ + c * 64) * 64;
  GLDS16(&Klds[tid * 8], kcb + tid * 8);
  GLDS16(&Klds[2048 + tid * 8], kcb + 2048 + tid * 8);
  __syncthreads();

  const int hij = (hh * 64 + i0m) * 64 + j4;
  const float4 r0 = *(const float4*)(retb + hij);
  const float4 r1 = *(const float4*)(retb + hij + 64);
  const float4 r2 = *(const float4*)(retb + hij + 128);
  const float4 r3 = *(const float4*)(retb + hij + 192);
  const float4 g0 = *(const float4*)(gamb + hij);
  const float4 g1 = *(const float4*)(gamb + hij + 64);
  const float4 g2 = *(const float4*)(gamb + hij + 128);
  const float4 g3 = *(const float4*)(gamb + hij + 192);
  const u16* vbp = vtb + ((size_t)bh * 64 + i0m) * L_ + c * 64;

  float4 s0 = {0,0,0,0}, s1 = {0,0,0,0}, s2 = {0,0,0,0}, s3 = {0,0,0,0};
#pragma unroll 1
  for (int t8 = 0; t8 < 8; ++t8) {
    const bf16x8 va = *(const bf16x8*)(vbp + t8 * 8);
    const bf16x8 vb = *(const bf16x8*)(vbp + L_ + t8 * 8);
    const bf16x8 vc = *(const bf16x8*)(vbp + 2 * L_ + t8 * 8);
    const bf16x8 vd = *(const bf16x8*)(vbp + 3 * L_ + t8 * 8);
#pragma unroll
    for (int tt = 0; tt < 8; ++tt) {
      const ushort4 k4u = *(const ushort4*)&Klds[(t8 * 8 + tt) * 64 + j4];
      const float kx = bf2f(k4u.x), ky = bf2f(k4u.y),
                  kz = bf2f(k4u.z), kw = bf2f(k4u.w);
      stp_upd1(s0, r0, g0, bf2f((u16)va[tt]), kx, ky, kz, kw);
      stp_upd1(s1, r1, g1, bf2f((u16)vb[tt]), kx, ky, kz, kw);
      stp_upd1(s2, r2, g2, bf2f((u16)vc[tt]), kx, ky, kz, kw);
      stp_upd1(s3, r3, g3, bf2f((u16)vd[tt]), kx, ky, kz, kw);
    }
  }
  float* sb = slocal + (((size_t)(bh * 32 + c) * 64) + i0m) * 64 + j4;
  *(float4*)(sb)       = s0;
  *(float4*)(sb + 64)  = s1;
  *(float4*)(sb + 128) = s2;
  *(float4*)(sb + 192) = s3;
}

// fused: attn split-kv (2048 blocks, KVBLK=128) + stp_pass1 (1024 blocks).
__global__ __launch_bounds__(256, 2) void attn_stp1_kernel(
    const u16* __restrict__ qb, const u16* __restrict__ kb,
    const u16* __restrict__ vtb, u16* __restrict__ osmb,
    float* __restrict__ mlb, const float* __restrict__ retb,
    const float* __restrict__ gamb, float* __restrict__ slocal) {
  __shared__ u16 sbuf[24576];  // 48KB union: attn Ks/Vts/Pl | pass1 Klds
  const int bid = blockIdx.x;
  if (bid < 2048) attn_body(bid, sbuf, qb, kb, vtb, osmb, mlb);
  else            stp1_body(bid - 2048, sbuf, kb, vtb, retb, gamb, slocal);
}

// Boundary scan: sequential over 32 chunks, parallel over (bh,i,j).
__global__ __launch_bounds__(256) void stp_scan(
    const float* __restrict__ retb64, float* __restrict__ slocal) {
  const int idx = blockIdx.x * 256 + threadIdx.x;  // 0..131071 = (bh,i,j)
  const int j = idx & 63, i1 = (idx >> 6) & 63, bh = idx >> 12;
  const int hh = bh & 15;
  const float r64 = retb64[(hh * 64 + i1) * 64 + j];
  float carry = 0.f;
  for (int c = 0; c < 32; ++c) {
    const size_t off = ((((size_t)bh * 32 + c) * 64 + i1) * 64 + j);
    const float sl = slocal[off];
    slocal[off] = carry;
    carry = fmaf(r64, carry, sl);
  }
}

// Pass 2 + FUSED BLEND (LDS-staged): the t-loop writes y_stp to LDS, then one
// barrier and a block-wide COALESCED epilogue does the split-kv combine (bf16
// normalized O, f32 weights) + gate and writes ycomb bf16.
__global__ __launch_bounds__(256, 4) void stp_pass2(
    const u16* __restrict__ qb, const u16* __restrict__ kb,
    const u16* __restrict__ vtb, const float* __restrict__ retb,
    const float* __restrict__ gamb, const float* __restrict__ wst,
    const float* __restrict__ slocal, const u16* __restrict__ osmb,
    const float* __restrict__ mlb, const float* __restrict__ alp,
    u16* __restrict__ ycomb) {
  __shared__ u16 KQ[8192];         // [0..4095] K, [4096..8191] Q
  __shared__ float ylds[4096];     // [t][dim] 64x64 f32 y_stp stage
  const int tid = threadIdx.x, lane = tid & 63, w = tid >> 6;
  const int bh = blockIdx.x >> 5, c = blockIdx.x & 31;
  const int hh = bh & 15;
  const int bb = bh >> 4;
  const int m = lane >> 4, jc = lane & 15, j4 = jc * 4;
  const int i0m = w * 16 + m * 4;

  const size_t cb = ((size_t)bh * L_ + c * 64) * 64;
  GLDS16(&KQ[tid * 8], kb + cb + tid * 8);
  GLDS16(&KQ[2048 + tid * 8], kb + cb + 2048 + tid * 8);
  GLDS16(&KQ[4096 + tid * 8], qb + cb + tid * 8);
  GLDS16(&KQ[6144 + tid * 8], qb + cb + 2048 + tid * 8);
  __syncthreads();

  const int hij = (hh * 64 + i0m) * 64 + j4;
  const float4 r0 = *(const float4*)(retb + hij);
  const float4 r1 = *(const float4*)(retb + hij + 64);
  const float4 r2 = *(const float4*)(retb + hij + 128);
  const float4 r3 = *(const float4*)(retb + hij + 192);
  const float4 g0 = *(const float4*)(gamb + hij);
  const float4 g1 = *(const float4*)(gamb + hij + 64);
  const float4 g2 = *(const float4*)(gamb + hij + 128);
  const float4 g3 = *(const float4*)(gamb + hij + 192);
  const float4 w0 = *(const float4*)(wst + hij);
  const float4 w1 = *(const float4*)(wst + hij + 64);
  const float4 w2 = *(const float4*)(wst + hij + 128);
  const float4 w3 = *(const float4*)(wst + hij + 192);

  const float* sb = slocal + (((size_t)(bh * 32 + c) * 64) + i0m) * 64 + j4;
  float4 z0 = *(const float4*)(sb);
  float4 z1 = *(const float4*)(sb + 64);
  float4 z2 = *(const float4*)(sb + 128);
  float4 z3 = *(const float4*)(sb + 192);

  float4 wlc0, wlc1, wlc2, wlc3;
  wlc0.x = w0.x * (1.f - r0.x); wlc0.y = w0.y * (1.f - r0.y);
  wlc0.z = w0.z * (1.f - r0.z); wlc0.w = w0.w * (1.f - r0.w);
  wlc1.x = w1.x * (1.f - r1.x); wlc1.y = w1.y * (1.f - r1.y);
  wlc1.z = w1.z * (1.f - r1.z); wlc1.w = w1.w * (1.f - r1.w);
  wlc2.x = w2.x * (1.f - r2.x); wlc2.y = w2.y * (1.f - r2.y);
  wlc2.z = w2.z * (1.f - r2.z); wlc2.w = w2.w * (1.f - r2.w);
  wlc3.x = w3.x * (1.f - r3.x); wlc3.y = w3.y * (1.f - r3.y);
  wlc3.z = w3.z * (1.f - r3.z); wlc3.w = w3.w * (1.f - r3.w);
  z0.x += w0.x; z0.y += w0.y; z0.z += w0.z; z0.w += w0.w;
  z1.x += w1.x; z1.y += w1.y; z1.z += w1.z; z1.w += w1.w;
  z2.x += w2.x; z2.y += w2.y; z2.z += w2.z; z2.w += w2.w;
  z3.x += w3.x; z3.y += w3.y; z3.z += w3.z; z3.w += w3.w;

  const u16* vbp = vtb + ((size_t)bh * 64 + i0m) * L_ + c * 64;

#pragma unroll 1
  for (int t8 = 0; t8 < 8; ++t8) {
    const bf16x8 va = *(const bf16x8*)(vbp + t8 * 8);
    const bf16x8 vb = *(const bf16x8*)(vbp + L_ + t8 * 8);
    const bf16x8 vc = *(const bf16x8*)(vbp + 2 * L_ + t8 * 8);
    const bf16x8 vd = *(const bf16x8*)(vbp + 3 * L_ + t8 * 8);
#pragma unroll
    for (int tt = 0; tt < 8; ++tt) {
      const int t = t8 * 8 + tt;
      const ushort4 k4u = *(const ushort4*)&KQ[t * 64 + j4];
      const ushort4 q4u = *(const ushort4*)&KQ[4096 + t * 64 + j4];
      const float kx = bf2f(k4u.x), ky = bf2f(k4u.y),
                  kz = bf2f(k4u.z), kw = bf2f(k4u.w);
      const float qx = bf2f(q4u.x), qy = bf2f(q4u.y),
                  qz = bf2f(q4u.z), qw = bf2f(q4u.w);
      stp_upd(z0, r0, g0, wlc0, bf2f((u16)va[tt]), kx, ky, kz, kw);
      stp_upd(z1, r1, g1, wlc1, bf2f((u16)vb[tt]), kx, ky, kz, kw);
      stp_upd(z2, r2, g2, wlc2, bf2f((u16)vc[tt]), kx, ky, kz, kw);
      stp_upd(z3, r3, g3, wlc3, bf2f((u16)vd[tt]), kx, ky, kz, kw);
      float p0 = dpp_red16(stp_dot(z0, qx, qy, qz, qw));
      float p1 = dpp_red16(stp_dot(z1, qx, qy, qz, qw));
      float p2 = dpp_red16(stp_dot(z2, qx, qy, qz, qw));
      float p3 = dpp_red16(stp_dot(z3, qx, qy, qz, qw));
      if (jc == 0) {
        float4 yo;  // y_stp = p*8 (undo qb's 0.125, exact pow2)
        yo.x = p0 * 8.f; yo.y = p1 * 8.f; yo.z = p2 * 8.f; yo.w = p3 * 8.f;
        *(float4*)&ylds[t * 64 + i0m] = yo;
      }
    }
  }

  __syncthreads();  // all waves' y_stp strips visible

  // Coalesced blend epilogue: 1024 float4-groups over 256 threads.
#pragma unroll
  for (int k2 = 0; k2 < 4; ++k2) {
    const int gi = k2 * 256 + tid;   // 0..1023
    const int t = gi >> 4;           // token within chunk
    const int d4 = (gi & 15) * 4;    // dim group
    const int ll = c * 64 + t;
    const int rowg = bh * L_ + ll;
    float m1 = mlb[rowg],          l1 = mlb[65536 + rowg];
    float m2 = mlb[131072 + rowg], l2 = mlb[196608 + rowg];
    float mm = fmaxf(m1, m2);
    float e1 = __expf(m1 - mm), e2 = __expf(m2 - mm);
    float inv = 1.f / fmaf(l1, e1, l2 * e2);
    float w1v = l1 * e1 * inv, w2v = l2 * e2 * inv;
    size_t bi = (size_t)rowg * 64 + d4;
    ushort4 o1u = *(const ushort4*)(osmb + bi);
    ushort4 o2u = *(const ushort4*)(osmb + 4194304 + bi);
    const int mtok = bb * L_ + ll;
    float a = alp[mtok * 16 + hh];
    const float na = 1.f - a;
    float4 ys = *(const float4*)&ylds[t * 64 + d4];
    ushort4 oo;
    oo.x = f2bf(a * (w1v * bf2f(o1u.x) + w2v * bf2f(o2u.x)) + na * ys.x);
    oo.y = f2bf(a * (w1v * bf2f(o1u.y) + w2v * bf2f(o2u.y)) + na * ys.y);
    oo.z = f2bf(a * (w1v * bf2f(o1u.z) + w2v * bf2f(o2u.z)) + na * ys.z);
    oo.w = f2bf(a * (w1v * bf2f(o1u.w) + w2v * bf2f(o2u.w)) + na * ys.w);
    *(ushort4*)(ycomb + (size_t)mtok * 1024 + hh * 64 + d4) = oo;
  }
}

// ---------------- launch ----------------

extern "C" void kernel_launch(void* const* d_in, const int* in_sizes, int n_in,
                              void* d_out, int out_size, void* d_ws, size_t ws_size,
                              hipStream_t stream) {
  const float* x       = (const float*)d_in[0];
  const float* wqkv_w  = (const float*)d_in[1];
  const float* wqkv_b  = (const float*)d_in[2];
  const float* out_w   = (const float*)d_in[3];
  const float* out_b   = (const float*)d_in[4];
  const float* w_stat  = (const float*)d_in[5];
  const float* lam     = (const float*)d_in[6];
  const float* gma     = (const float*)d_in[7];
  const float* g_w1    = (const float*)d_in[8];
  const float* g_b1    = (const float*)d_in[9];
  const float* g_w2    = (const float*)d_in[10];
  const float* g_b2    = (const float*)d_in[11];

  char* ws = (char*)d_ws;
  size_t off = 0;
  auto nxt = [&](size_t b) { size_t r = off; off += (b + 255) & ~(size_t)255; return r; };
  u16*   xbf   = (u16*)(ws + nxt((size_t)4096 * 1024 * 2));
  u16*   wqkvT = (u16*)(ws + nxt((size_t)3072 * 1024 * 2));
  u16*   owT   = (u16*)(ws + nxt((size_t)1024 * 1024 * 2));
  u16*   g1T   = (u16*)(ws + nxt((size_t)512 * 1024 * 2));
  u16*   qb    = (u16*)(ws + nxt((size_t)4194304 * 2));
  u16*   kb    = (u16*)(ws + nxt((size_t)4194304 * 2));
  u16*   vtb   = (u16*)(ws + nxt((size_t)4194304 * 2));
  u16*   osmb  = (u16*)(ws + nxt((size_t)2 * 4194304 * 2));   // 2 halves, bf16 O/l
  float* mlb   = (float*)(ws + nxt((size_t)4 * 65536 * 4));   // m/l per half
  // NO aliases: hbuf, ycomb, slocal all private.
  float* hbuf  = (float*)(ws + nxt((size_t)4096 * 512 * 4));   // 8MB
  u16*   ycomb = (u16*)(ws + nxt((size_t)4096 * 1024 * 2));    // 8MB
  float* slocal= (float*)(ws + nxt((size_t)4194304 * 4));      // 16MB
  float* alp   = (float*)(ws + nxt((size_t)4096 * 16 * 4));
  float* retb  = (float*)(ws + nxt((size_t)65536 * 4));
  float* gamb  = (float*)(ws + nxt((size_t)65536 * 4));
  float* retb64= (float*)(ws + nxt((size_t)65536 * 4));

  dim3 blk(256);
  prep_fused<<<8960, blk, 0, stream>>>(x, xbf, wqkv_w, wqkvT, out_w, owT,
                                       g_w1, g1T, lam, gma, retb, gamb, retb64);

  GemmP p0 = {xbf, wqkvT, 4096, 3072, 1024, wqkv_b,
              qb, kb, vtb, nullptr, nullptr};
  GemmP p1 = {xbf, g1T, 4096, 512, 1024, g_b1,
              nullptr, nullptr, nullptr, hbuf, nullptr};
  gemm01_kernel<<<896, blk, 0, stream>>>(p0, p1);

  alpha_kernel<<<256, blk, 0, stream>>>(hbuf, g_w2, g_b2, alp);

  // attn split-kv KVBLK=128 (2048) + stp_pass1 (1024)
  attn_stp1_kernel<<<3072, blk, 0, stream>>>(qb, kb, vtb, osmb, mlb,
                                             retb, gamb, slocal);

  stp_scan<<<512, blk, 0, stream>>>(retb64, slocal);

  // pass2 with LDS-staged fused blend: writes ycomb directly.
  stp_pass2<<<1024, blk, 0, stream>>>(qb, kb, vtb, retb, gamb, w_stat,
                                      slocal, osmb, mlb, alp, ycomb);

  GemmP p2 = {ycomb, owT, 4096, 1024, 1024, out_b,
              nullptr, nullptr, nullptr, nullptr, (float*)d_out};
  gemm2_kernel<<<dim3(8, 32), blk, 0, stream>>>(p2);
}

// Round 25
// 220.527 us; speedup vs baseline: 1.0520x; 1.0308x over previous
//
#include <hip/hip_runtime.h>
#include <cstdint>
#include <cstddef>

#define B_ 2
#define L_ 2048
#define D_ 1024
#define H_ 16
#define DH 64

typedef __attribute__((ext_vector_type(8))) short bf16x8;
typedef __attribute__((ext_vector_type(4))) float f32x4;
typedef unsigned short u16;

__device__ inline u16 f2bf(float f) {
  unsigned u = __builtin_bit_cast(unsigned, f);
  u += 0x7fffu + ((u >> 16) & 1u);
  return (u16)(u >> 16);
}

__device__ inline float bf2f(u16 x) {
  return __builtin_bit_cast(float, (unsigned)x << 16);
}

// DPP lane-move (VALU pipe). Returns src shuffled per CTRL; full masks.
template <int CTRL>
__device__ inline float dpp_mov(float x) {
  int t = __builtin_amdgcn_update_dpp(0, __builtin_bit_cast(int, x), CTRL, 0xf, 0xf, true);
  return __builtin_bit_cast(float, t);
}

// global -> LDS direct (16B per lane). Staging layout must be linear in lane.
#define GLDS16(ldst, gsrc)                                              \
  __builtin_amdgcn_global_load_lds(                                    \
      (const __attribute__((address_space(1))) void*)(gsrc),           \
      (__attribute__((address_space(3))) void*)(ldst), 16, 0, 0)

// STP row helpers
__device__ inline void stp_upd(float4& z, const float4 r, const float4 g,
                               const float4 wlc, float vv,
                               float kx, float ky, float kz, float kw) {
  z.x = fmaf(r.x, z.x, fmaf(g.x * vv, kx, wlc.x));
  z.y = fmaf(r.y, z.y, fmaf(g.y * vv, ky, wlc.y));
  z.z = fmaf(r.z, z.z, fmaf(g.z * vv, kz, wlc.z));
  z.w = fmaf(r.w, z.w, fmaf(g.w * vv, kw, wlc.w));
}

__device__ inline void stp_upd1(float4& z, const float4 r, const float4 g,
                                float vv, float kx, float ky, float kz, float kw) {
  z.x = fmaf(r.x, z.x, (g.x * vv) * kx);
  z.y = fmaf(r.y, z.y, (g.y * vv) * ky);
  z.z = fmaf(r.z, z.z, (g.z * vv) * kz);
  z.w = fmaf(r.w, z.w, (g.w * vv) * kw);
}

__device__ inline float stp_dot(const float4 z, float qx, float qy, float qz, float qw) {
  float p = z.x * qx;
  p = fmaf(z.y, qy, p);
  p = fmaf(z.z, qz, p);
  p = fmaf(z.w, qw, p);
  return p;
}

__device__ inline float dpp_red16(float p) {
  p = p + dpp_mov<0x128>(p);  // row_ror:8 (16-lane closure)
  p = p + dpp_mov<0x124>(p);
  p = p + dpp_mov<0x122>(p);
  p = p + dpp_mov<0x121>(p);
  return p;
}

// ---------------- fused prep kernel (block-range dispatch) ----------------

__device__ inline void d_transpose(const float* __restrict__ in,
                                   u16* __restrict__ out, int R, int C,
                                   int bx, int by, float tile[32][33], int tid) {
  const int tx = tid & 31, ty = tid >> 5;
  const int c0 = bx * 32, r0 = by * 32;
#pragma unroll
  for (int j = 0; j < 4; ++j)
    tile[ty + j * 8][tx] = in[(size_t)(r0 + ty + j * 8) * C + c0 + tx];
  __syncthreads();
#pragma unroll
  for (int j = 0; j < 4; ++j)
    out[(size_t)(c0 + ty + j * 8) * R + r0 + tx] = f2bf(tile[tx][ty + j * 8]);
}

__global__ __launch_bounds__(256) void prep_fused(
    const float* __restrict__ x, u16* __restrict__ xbf,
    const float* __restrict__ wqkv_w, u16* __restrict__ wqkvT,
    const float* __restrict__ out_w, u16* __restrict__ owT,
    const float* __restrict__ g_w1, u16* __restrict__ g1T,
    const float* __restrict__ lam, const float* __restrict__ gma,
    float* __restrict__ retb, float* __restrict__ gamb,
    float* __restrict__ retb64) {
  __shared__ float tile[32][33];
  const int bid = blockIdx.x, tid = threadIdx.x;
  if (bid < 4096) {
    int i = bid * 256 + tid;
    float4 v = ((const float4*)x)[i];
    ushort4 o;
    o.x = f2bf(v.x); o.y = f2bf(v.y); o.z = f2bf(v.z); o.w = f2bf(v.w);
    ((ushort4*)xbf)[i] = o;
  } else if (bid < 7168) {
    int r = bid - 4096;
    d_transpose(wqkv_w, wqkvT, 1024, 3072, r % 96, r / 96, tile, tid);
  } else if (bid < 8192) {
    int r = bid - 7168;
    d_transpose(out_w, owT, 1024, 1024, r % 32, r / 32, tile, tid);
  } else if (bid < 8704) {
    int r = bid - 8192;
    d_transpose(g_w1, g1T, 1024, 512, r % 16, r / 16, tile, tid);
  } else {
    int i = (bid - 8704) * 256 + tid;  // 65536 total
    float l = lam[i];
    float r = 1.f / (1.f + expf(l));   // 1 - sigmoid(l)
    retb[i] = r;
    gamb[i] = gma[i] * 0.125f;         // fold k-scale into Gamma
    float r2 = r * r;                   // r^64 by 6 squarings
    float r4 = r2 * r2;
    float r8 = r4 * r4;
    float r16 = r8 * r8;
    float r32 = r16 * r16;
    retb64[i] = r32 * r32;
  }
}

// ---------------- GEMM body (C = A @ Bt^T), 64x128 tile, BK=64 ---------------
// Smaller M-tile doubles grid (occupancy-fills CUs; both GEMMs were
// grid-limited). Chunk-swizzle (rule 21c) on As/Bs; tileT aliases As/Bs for
// EPI0's v-epilogue (single pass: 64 rows fit at once).

struct GemmP {
  const u16* A; const u16* Bt; int M, N, K;
  const float* bias;
  u16* qb; u16* kb; u16* vtb;  // EPI 0
  float* hout;                 // EPI 1
  float* outp;                 // EPI 2
};

template <int EPI>
__device__ void gemm_body(const GemmP& p, int lin0, int nwgx, int nwgtot,
                          u16* As, u16* Bs, u16* tileT) {
  const int tid = threadIdx.x;
  const int lane = tid & 63;
  const int w = tid >> 6;
  const int wr = w >> 1, wc = w & 1;   // wave covers 32 rows x 64 cols
  const int lr = lane & 15, lk = lane >> 4;
  // XCD-aware tile remap (T1): nwgtot % 8 == 0 for all our grids.
  const int cpx = nwgtot >> 3;
  const int lin = (lin0 & 7) * cpx + (lin0 >> 3);
  const int m0 = (lin / nwgx) * 64, n0 = (lin % nwgx) * 128;

  f32x4 acc[2][4];
#pragma unroll
  for (int i = 0; i < 2; ++i)
#pragma unroll
    for (int j = 0; j < 4; ++j) acc[i][j] = (f32x4){0.f, 0.f, 0.f, 0.f};

  for (int k0 = 0; k0 < p.K; k0 += 64) {
    __syncthreads();
    // As: 64 rows x 8 chunks = 512; Bs: 128 rows x 8 chunks = 1024.
#pragma unroll
    for (int it = 0; it < 2; ++it) {
      int idx = it * 256 + tid;               // 0..511
      int row = idx >> 3;
      int ch = (idx & 7) ^ (row & 7);         // inverse-swizzled source chunk
      GLDS16(&As[idx * 8], p.A + (size_t)(m0 + row) * p.K + k0 + ch * 8);
    }
#pragma unroll
    for (int it = 0; it < 4; ++it) {
      int idx = it * 256 + tid;               // 0..1023
      int row = idx >> 3;
      int ch = (idx & 7) ^ (row & 7);
      GLDS16(&Bs[idx * 8], p.Bt + (size_t)(n0 + row) * p.K + k0 + ch * 8);
    }
    __syncthreads();
#pragma unroll
    for (int kk = 0; kk < 2; ++kk) {
      const int slot = ((kk * 4 + lk) ^ (lr & 7)) * 8;
      bf16x8 af[2], bfr[4];
#pragma unroll
      for (int mr = 0; mr < 2; ++mr)
        af[mr] = *(const bf16x8*)&As[(wr * 32 + mr * 16 + lr) * 64 + slot];
#pragma unroll
      for (int nr = 0; nr < 4; ++nr)
        bfr[nr] = *(const bf16x8*)&Bs[(wc * 64 + nr * 16 + lr) * 64 + slot];
#pragma unroll
      for (int mr = 0; mr < 2; ++mr)
#pragma unroll
        for (int nr = 0; nr < 4; ++nr)
          acc[mr][nr] = __builtin_amdgcn_mfma_f32_16x16x32_bf16(af[mr], bfr[nr], acc[mr][nr], 0, 0, 0);
    }
  }

  if constexpr (EPI == 0) {
    if (n0 < 2048) {
#pragma unroll
      for (int mr = 0; mr < 2; ++mr)
#pragma unroll
        for (int nr = 0; nr < 4; ++nr) {
          const int col = n0 + wc * 64 + nr * 16 + lr;
#pragma unroll
          for (int rr = 0; rr < 4; ++rr) {
            const int row = m0 + wr * 32 + mr * 16 + lk * 4 + rr;
            float v = acc[mr][nr][rr] + p.bias[col];
            int which = col >> 10, hh = (col >> 6) & 15, ii = col & 63;
            int b = row >> 11, ll = row & 2047;
            size_t bi = ((size_t)(b * 16 + hh) * L_ + ll) * 64 + ii;
            if (which == 0) p.qb[bi] = f2bf(v * 0.125f);
            else            p.kb[bi] = f2bf(v);
          }
        }
    } else {
      // v region: single-pass LDS transpose (tileT aliases As/Bs).
      __syncthreads();  // As/Bs reads done
#pragma unroll
      for (int mr = 0; mr < 2; ++mr)
#pragma unroll
        for (int nr = 0; nr < 4; ++nr) {
          const int cl = wc * 64 + nr * 16 + lr;
          const float bv = p.bias[n0 + cl];
#pragma unroll
          for (int rr = 0; rr < 4; ++rr) {
            const int rl = wr * 32 + mr * 16 + lk * 4 + rr;  // 0..63
            tileT[cl * 72 + rl] = f2bf(acc[mr][nr][rr] + bv);
          }
        }
      __syncthreads();
      // coalesced 16B stores: 128 cols x 64 token-rows
      const int c = tid >> 1, half = tid & 1;
      const int vcol = (n0 - 2048) + c;
      const int hh = vcol >> 6, ii = vcol & 63;
      const int b = m0 >> 11;
      const int ll0 = (m0 & 2047) + half * 32;
      u16* dst = p.vtb + ((size_t)(b * 16 + hh) * 64 + ii) * L_ + ll0;
      const u16* src = &tileT[c * 72 + half * 32];
#pragma unroll
      for (int k = 0; k < 4; ++k)
        *(int4*)(dst + k * 8) = *(const int4*)(src + k * 8);
    }
  } else {
#pragma unroll
    for (int mr = 0; mr < 2; ++mr)
#pragma unroll
      for (int nr = 0; nr < 4; ++nr) {
        const int col = n0 + wc * 64 + nr * 16 + lr;
#pragma unroll
        for (int rr = 0; rr < 4; ++rr) {
          const int row = m0 + wr * 32 + mr * 16 + lk * 4 + rr;
          float v = acc[mr][nr][rr] + p.bias[col];
          if constexpr (EPI == 1) {
            float g = 0.5f * v * (1.f + erff(v * 0.70710678118f));  // exact gelu
            p.hout[(size_t)row * p.N + col] = g;
          } else {
            p.outp[(size_t)row * p.N + col] = v;
          }
        }
      }
  }
}

// fused gemm<0> (1536 blocks) + gemm<1> (256 blocks): both read xbf only.
// LDS: As(4096 u16) + Bs(8192 u16) = 24KB; tileT(9216 u16) aliases.
__global__ __launch_bounds__(256, 4) void gemm01_kernel(GemmP p0, GemmP p1) {
  __shared__ u16 sbuf[12288];
  u16* As = sbuf;
  u16* Bs = sbuf + 4096;
  u16* tileT = sbuf;
  const int bid = blockIdx.x;
  if (bid < 1536) gemm_body<0>(p0, bid, 24, 1536, As, Bs, tileT);
  else            gemm_body<1>(p1, bid - 1536, 4, 256, As, Bs, tileT);
}

// standalone gemm<2> (out proj): 64x128 tiles -> 512 blocks (was 256).
__global__ __launch_bounds__(256, 4) void gemm2_kernel(GemmP p) {
  __shared__ u16 As[4096];
  __shared__ u16 Bs[8192];
  gemm_body<2>(p, (int)blockIdx.x, 8, 512, As, Bs, nullptr);
}

// ---------------- gate alpha: sigmoid(h @ w2 + b2) ----------------

__global__ __launch_bounds__(256) void alpha_kernel(
    const float* __restrict__ hbuf, const float* __restrict__ w2,
    const float* __restrict__ b2, float* __restrict__ alp) {
  const int tid = threadIdx.x;
  const int row = blockIdx.x * 16 + (tid >> 4);
  const int n = tid & 15;
  const float4* h4 = (const float4*)(hbuf + (size_t)row * 512);
  float acc = 0.f;
#pragma unroll 2
  for (int kk = 0; kk < 128; ++kk) {
    float4 hv = h4[kk];
    acc = fmaf(hv.x, w2[(kk * 4 + 0) * 16 + n], acc);
    acc = fmaf(hv.y, w2[(kk * 4 + 1) * 16 + n], acc);
    acc = fmaf(hv.z, w2[(kk * 4 + 2) * 16 + n], acc);
    acc = fmaf(hv.w, w2[(kk * 4 + 3) * 16 + n], acc);
  }
  float z = acc + b2[n];
  alp[row * 16 + n] = 1.f / (1.f + __expf(-z));
}

// ---------------- flash attention body (split-kv, KVBLK=128, bf16 O) ---------
// sbuf carve: Ks = [0,8192) [128][64], Vts = [8192,16384) [64][128],
// Pl = [16384,24576) [4][16][128]. All XOR-swizzled.

__device__ void attn_body(int lin, u16* sbuf,
                          const u16* __restrict__ qb, const u16* __restrict__ kb,
                          const u16* __restrict__ vtb, u16* __restrict__ osmb,
                          float* __restrict__ mlb) {
  u16* Ks = sbuf;
  u16* Vts = sbuf + 8192;
  u16* Pl = sbuf + 16384;
  const int tid = threadIdx.x, lane = tid & 63, w = tid >> 6;
  const int lr = lane & 15, lk = lane >> 4;
  const int bh = lin & 31;
  const int rest = lin >> 5;           // 0..63
  const int qt = 31 - (rest >> 1);     // heavy (large qt) first
  const int half = rest & 1;
  const int ktot = (qt >> 1) + 1;      // 128-tiles covering [0, (qt+1)*64)
  const int hs = (ktot + 1) >> 1;      // split point
  const int kt0 = half ? hs : 0;
  const int kt1 = half ? ktot : hs;

  const u16* kbase0 = kb + (size_t)bh * (L_ * 64);
  const u16* vbase0 = vtb + (size_t)bh * (64 * L_);

  const size_t qbase = ((size_t)bh * L_ + qt * 64 + w * 16 + lr) * 64;
  bf16x8 qfr[2];
  qfr[0] = *(const bf16x8*)(qb + qbase + lk * 8);
  qfr[1] = *(const bf16x8*)(qb + qbase + 32 + lk * 8);

  f32x4 yacc[4];
  float mrow[4], lrow[4];
#pragma unroll
  for (int i = 0; i < 4; ++i) {
    yacc[i] = (f32x4){0.f, 0.f, 0.f, 0.f};
    mrow[i] = -1e30f;
    lrow[i] = 0.f;
  }

  for (int kt = kt0; kt < kt1; ++kt) {
    const int kv0 = kt * 128;
    __syncthreads();
#pragma unroll
    for (int it = 0; it < 4; ++it) {
      int idx = it * 256 + tid;            // 0..1023
      int krow = idx >> 3, kch = idx & 7;  // K: 128 rows x 8 chunks
      *(int4*)&Ks[krow * 64 + ((kch ^ (krow & 7)) * 8)] =
          *(const int4*)(kbase0 + (size_t)(kv0 + krow) * 64 + kch * 8);
      int vrow = idx >> 4, vch = idx & 15; // Vt: 64 rows x 16 chunks
      *(int4*)&Vts[vrow * 128 + ((vch ^ (vrow & 15)) * 8)] =
          *(const int4*)(vbase0 + (size_t)vrow * L_ + kv0 + vch * 8);
    }
    __syncthreads();

    // QK^T: s[f] covers kv cols kv0 + f*16+lr
    f32x4 s[8];
#pragma unroll
    for (int f = 0; f < 8; ++f) {
      f32x4 sf = (f32x4){0.f, 0.f, 0.f, 0.f};
#pragma unroll
      for (int ss = 0; ss < 2; ++ss) {
        bf16x8 kfr = *(const bf16x8*)&Ks[(f * 16 + lr) * 64 +
                                         (((ss * 4 + lk) ^ (lr & 7)) * 8)];
        sf = __builtin_amdgcn_mfma_f32_16x16x32_bf16(qfr[ss], kfr, sf, 0, 0, 0);
      }
      s[f] = sf;
    }
    if (kt == ktot - 1) {  // last tile: mask global col > row
      const int rowg0 = qt * 64 + w * 16 + lk * 4;
#pragma unroll
      for (int f = 0; f < 8; ++f) {
        const int colg = kv0 + f * 16 + lr;
#pragma unroll
        for (int rr = 0; rr < 4; ++rr)
          if (colg > rowg0 + rr) s[f][rr] = -1e30f;
      }
    }
    // tile max per row (16-lane DPP closure)
    float mx[4];
#pragma unroll
    for (int rr = 0; rr < 4; ++rr) {
      float m = s[0][rr];
#pragma unroll
      for (int f = 1; f < 8; ++f) m = fmaxf(m, s[f][rr]);
      m = fmaxf(m, dpp_mov<0x128>(m));
      m = fmaxf(m, dpp_mov<0x124>(m));
      m = fmaxf(m, dpp_mov<0x122>(m));
      m = fmaxf(m, dpp_mov<0x121>(m));
      mx[rr] = m;
    }
    // defer-max (T13): skip rescale unless a row grew by > 8 (exact skip).
    bool need = (mx[0] > mrow[0] + 8.f) | (mx[1] > mrow[1] + 8.f) |
                (mx[2] > mrow[2] + 8.f) | (mx[3] > mrow[3] + 8.f);
    if (__any(need)) {
#pragma unroll
      for (int rr = 0; rr < 4; ++rr) {
        float mn = fmaxf(mrow[rr], mx[rr]);
        float c = __expf(mrow[rr] - mn);
        lrow[rr] *= c;
#pragma unroll
        for (int nf = 0; nf < 4; ++nf) yacc[nf][rr] *= c;
        mrow[rr] = mn;
      }
    }
    // exp fused with P-store (swizzled, 16-chunk rows); row-sum via DPP.
    u16* pw = Pl + w * 2048;
#pragma unroll
    for (int rr = 0; rr < 4; ++rr) {
      const int prow = lk * 4 + rr;
      float rs = 0.f;
#pragma unroll
      for (int f = 0; f < 8; ++f) {
        float pv = __expf(s[f][rr] - mrow[rr]);
        rs += pv;
        int chunk = f * 2 + (lr >> 3);
        pw[prow * 128 + ((chunk ^ prow) * 8) + (lr & 7)] = f2bf(pv);
      }
      rs = rs + dpp_mov<0x128>(rs);
      rs = rs + dpp_mov<0x124>(rs);
      rs = rs + dpp_mov<0x122>(rs);
      rs = rs + dpp_mov<0x121>(rs);
      lrow[rr] += rs;
    }
    // PV: yacc[nf] += P[16 x 128] * Vt[d rows][128 kv]
#pragma unroll
    for (int s2 = 0; s2 < 4; ++s2) {
      bf16x8 pa = *(const bf16x8*)&pw[lr * 128 + (((s2 * 4 + lk) ^ lr) * 8)];
#pragma unroll
      for (int nf = 0; nf < 4; ++nf) {
        bf16x8 vfr = *(const bf16x8*)&Vts[(nf * 16 + lr) * 128 +
                                          (((s2 * 4 + lk) ^ lr) * 8)];
        yacc[nf] = __builtin_amdgcn_mfma_f32_16x16x32_bf16(pa, vfr, yacc[nf], 0, 0, 0);
      }
    }
  }

  // store NORMALIZED O (bf16) + per-row (m,l). Empty half: l=0 -> store 0.
  float invl[4];
#pragma unroll
  for (int rr = 0; rr < 4; ++rr)
    invl[rr] = lrow[rr] > 0.f ? 1.f / lrow[rr] : 0.f;
  u16* obase = osmb + (size_t)half * 4194304;
#pragma unroll
  for (int nf = 0; nf < 4; ++nf)
#pragma unroll
    for (int rr = 0; rr < 4; ++rr) {
      int rowl = w * 16 + lk * 4 + rr;
      int col = nf * 16 + lr;
      obase[((size_t)bh * L_ + qt * 64 + rowl) * 64 + col] =
          f2bf(yacc[nf][rr] * invl[rr]);
    }
  if (lr == 0) {
    const int rbase = bh * L_ + qt * 64 + w * 16 + lk * 4;
#pragma unroll
    for (int rr = 0; rr < 4; ++rr) {
      mlb[half * 131072 + rbase + rr] = mrow[rr];
      mlb[half * 131072 + 65536 + rbase + rr] = lrow[rr];
    }
  }
}

// ---------------- STP pass1 body (Klds = sbuf[0,4096)) -----------------------

__device__ void stp1_body(int bid, u16* Klds,
                          const u16* __restrict__ kb, const u16* __restrict__ vtb,
                          const float* __restrict__ retb,
                          const float* __restrict__ gamb,
                          float* __restrict__ slocal) {
  const int tid = threadIdx.x, lane = tid & 63, w = tid >> 6;
  const int bh = bid >> 5, c = bid & 31;
  const int hh = bh & 15;
  const int m = lane >> 4, j4 = (lane & 15) * 4;
  const int i0m = w * 16 + m * 4;

  const u16* kcb = kb + ((size_t)bh * L_ + c * 64) * 64;
  GLDS16(&Klds[tid * 8], kcb + tid * 8);
  GLDS16(&Klds[2048 + tid * 8], kcb + 2048 + tid * 8);
  __syncthreads();

  const int hij = (hh * 64 + i0m) * 64 + j4;
  const float4 r0 = *(const float4*)(retb + hij);
  const float4 r1 = *(const float4*)(retb + hij + 64);
  const float4 r2 = *(const float4*)(retb + hij + 128);
  const float4 r3 = *(const float4*)(retb + hij + 192);
  const float4 g0 = *(const float4*)(gamb + hij);
  const float4 g1 = *(const float4*)(gamb + hij + 64);
  const float4 g2 = *(const float4*)(gamb + hij + 128);
  const float4 g3 = *(const float4*)(gamb + hij + 192);
  const u16* vbp = vtb + ((size_t)bh * 64 + i0m) * L_ + c * 64;

  float4 s0 = {0,0,0,0}, s1 = {0,0,0,0}, s2 = {0,0,0,0}, s3 = {0,0,0,0};
#pragma unroll 1
  for (int t8 = 0; t8 < 8; ++t8) {
    const bf16x8 va = *(const bf16x8*)(vbp + t8 * 8);
    const bf16x8 vb = *(const bf16x8*)(vbp + L_ + t8 * 8);
    const bf16x8 vc = *(const bf16x8*)(vbp + 2 * L_ + t8 * 8);
    const bf16x8 vd = *(const bf16x8*)(vbp + 3 * L_ + t8 * 8);
#pragma unroll
    for (int tt = 0; tt < 8; ++tt) {
      const ushort4 k4u = *(const ushort4*)&Klds[(t8 * 8 + tt) * 64 + j4];
      const float kx = bf2f(k4u.x), ky = bf2f(k4u.y),
                  kz = bf2f(k4u.z), kw = bf2f(k4u.w);
      stp_upd1(s0, r0, g0, bf2f((u16)va[tt]), kx, ky, kz, kw);
      stp_upd1(s1, r1, g1, bf2f((u16)vb[tt]), kx, ky, kz, kw);
      stp_upd1(s2, r2, g2, bf2f((u16)vc[tt]), kx, ky, kz, kw);
      stp_upd1(s3, r3, g3, bf2f((u16)vd[tt]), kx, ky, kz, kw);
    }
  }
  float* sb = slocal + (((size_t)(bh * 32 + c) * 64) + i0m) * 64 + j4;
  *(float4*)(sb)       = s0;
  *(float4*)(sb + 64)  = s1;
  *(float4*)(sb + 128) = s2;
  *(float4*)(sb + 192) = s3;
}

// fused: attn split-kv (2048 blocks, KVBLK=128) + stp_pass1 (1024 blocks).
__global__ __launch_bounds__(256, 2) void attn_stp1_kernel(
    const u16* __restrict__ qb, const u16* __restrict__ kb,
    const u16* __restrict__ vtb, u16* __restrict__ osmb,
    float* __restrict__ mlb, const float* __restrict__ retb,
    const float* __restrict__ gamb, float* __restrict__ slocal) {
  __shared__ u16 sbuf[24576];  // 48KB union: attn Ks/Vts/Pl | pass1 Klds
  const int bid = blockIdx.x;
  if (bid < 2048) attn_body(bid, sbuf, qb, kb, vtb, osmb, mlb);
  else            stp1_body(bid - 2048, sbuf, kb, vtb, retb, gamb, slocal);
}

// Boundary scan: sequential over 32 chunks, parallel over (bh,i,j).
__global__ __launch_bounds__(256) void stp_scan(
    const float* __restrict__ retb64, float* __restrict__ slocal) {
  const int idx = blockIdx.x * 256 + threadIdx.x;  // 0..131071 = (bh,i,j)
  const int j = idx & 63, i1 = (idx >> 6) & 63, bh = idx >> 12;
  const int hh = bh & 15;
  const float r64 = retb64[(hh * 64 + i1) * 64 + j];
  float carry = 0.f;
  for (int c = 0; c < 32; ++c) {
    const size_t off = ((((size_t)bh * 32 + c) * 64 + i1) * 64 + j);
    const float sl = slocal[off];
    slocal[off] = carry;
    carry = fmaf(r64, carry, sl);
  }
}

// Pass 2 + FUSED BLEND (LDS-staged): the t-loop writes y_stp to LDS, then one
// barrier and a block-wide COALESCED epilogue does the split-kv combine (bf16
// normalized O, f32 weights) + gate and writes ycomb bf16.
__global__ __launch_bounds__(256, 4) void stp_pass2(
    const u16* __restrict__ qb, const u16* __restrict__ kb,
    const u16* __restrict__ vtb, const float* __restrict__ retb,
    const float* __restrict__ gamb, const float* __restrict__ wst,
    const float* __restrict__ slocal, const u16* __restrict__ osmb,
    const float* __restrict__ mlb, const float* __restrict__ alp,
    u16* __restrict__ ycomb) {
  __shared__ u16 KQ[8192];         // [0..4095] K, [4096..8191] Q
  __shared__ float ylds[4096];     // [t][dim] 64x64 f32 y_stp stage
  const int tid = threadIdx.x, lane = tid & 63, w = tid >> 6;
  const int bh = blockIdx.x >> 5, c = blockIdx.x & 31;
  const int hh = bh & 15;
  const int bb = bh >> 4;
  const int m = lane >> 4, jc = lane & 15, j4 = jc * 4;
  const int i0m = w * 16 + m * 4;

  const size_t cb = ((size_t)bh * L_ + c * 64) * 64;
  GLDS16(&KQ[tid * 8], kb + cb + tid * 8);
  GLDS16(&KQ[2048 + tid * 8], kb + cb + 2048 + tid * 8);
  GLDS16(&KQ[4096 + tid * 8], qb + cb + tid * 8);
  GLDS16(&KQ[6144 + tid * 8], qb + cb + 2048 + tid * 8);
  __syncthreads();

  const int hij = (hh * 64 + i0m) * 64 + j4;
  const float4 r0 = *(const float4*)(retb + hij);
  const float4 r1 = *(const float4*)(retb + hij + 64);
  const float4 r2 = *(const float4*)(retb + hij + 128);
  const float4 r3 = *(const float4*)(retb + hij + 192);
  const float4 g0 = *(const float4*)(gamb + hij);
  const float4 g1 = *(const float4*)(gamb + hij + 64);
  const float4 g2 = *(const float4*)(gamb + hij + 128);
  const float4 g3 = *(const float4*)(gamb + hij + 192);
  const float4 w0 = *(const float4*)(wst + hij);
  const float4 w1 = *(const float4*)(wst + hij + 64);
  const float4 w2 = *(const float4*)(wst + hij + 128);
  const float4 w3 = *(const float4*)(wst + hij + 192);

  const float* sb = slocal + (((size_t)(bh * 32 + c) * 64) + i0m) * 64 + j4;
  float4 z0 = *(const float4*)(sb);
  float4 z1 = *(const float4*)(sb + 64);
  float4 z2 = *(const float4*)(sb + 128);
  float4 z3 = *(const float4*)(sb + 192);

  float4 wlc0, wlc1, wlc2, wlc3;
  wlc0.x = w0.x * (1.f - r0.x); wlc0.y = w0.y * (1.f - r0.y);
  wlc0.z = w0.z * (1.f - r0.z); wlc0.w = w0.w * (1.f - r0.w);
  wlc1.x = w1.x * (1.f - r1.x); wlc1.y = w1.y * (1.f - r1.y);
  wlc1.z = w1.z * (1.f - r1.z); wlc1.w = w1.w * (1.f - r1.w);
  wlc2.x = w2.x * (1.f - r2.x); wlc2.y = w2.y * (1.f - r2.y);
  wlc2.z = w2.z * (1.f - r2.z); wlc2.w = w2.w * (1.f - r2.w);
  wlc3.x = w3.x * (1.f - r3.x); wlc3.y = w3.y * (1.f - r3.y);
  wlc3.z = w3.z * (1.f - r3.z); wlc3.w = w3.w * (1.f - r3.w);
  z0.x += w0.x; z0.y += w0.y; z0.z += w0.z; z0.w += w0.w;
  z1.x += w1.x; z1.y += w1.y; z1.z += w1.z; z1.w += w1.w;
  z2.x += w2.x; z2.y += w2.y; z2.z += w2.z; z2.w += w2.w;
  z3.x += w3.x; z3.y += w3.y; z3.z += w3.z; z3.w += w3.w;

  const u16* vbp = vtb + ((size_t)bh * 64 + i0m) * L_ + c * 64;

#pragma unroll 1
  for (int t8 = 0; t8 < 8; ++t8) {
    const bf16x8 va = *(const bf16x8*)(vbp + t8 * 8);
    const bf16x8 vb = *(const bf16x8*)(vbp + L_ + t8 * 8);
    const bf16x8 vc = *(const bf16x8*)(vbp + 2 * L_ + t8 * 8);
    const bf16x8 vd = *(const bf16x8*)(vbp + 3 * L_ + t8 * 8);
#pragma unroll
    for (int tt = 0; tt < 8; ++tt) {
      const int t = t8 * 8 + tt;
      const ushort4 k4u = *(const ushort4*)&KQ[t * 64 + j4];
      const ushort4 q4u = *(const ushort4*)&KQ[4096 + t * 64 + j4];
      const float kx = bf2f(k4u.x), ky = bf2f(k4u.y),
                  kz = bf2f(k4u.z), kw = bf2f(k4u.w);
      const float qx = bf2f(q4u.x), qy = bf2f(q4u.y),
                  qz = bf2f(q4u.z), qw = bf2f(q4u.w);
      stp_upd(z0, r0, g0, wlc0, bf2f((u16)va[tt]), kx, ky, kz, kw);
      stp_upd(z1, r1, g1, wlc1, bf2f((u16)vb[tt]), kx, ky, kz, kw);
      stp_upd(z2, r2, g2, wlc2, bf2f((u16)vc[tt]), kx, ky, kz, kw);
      stp_upd(z3, r3, g3, wlc3, bf2f((u16)vd[tt]), kx, ky, kz, kw);
      float p0 = dpp_red16(stp_dot(z0, qx, qy, qz, qw));
      float p1 = dpp_red16(stp_dot(z1, qx, qy, qz, qw));
      float p2 = dpp_red16(stp_dot(z2, qx, qy, qz, qw));
      float p3 = dpp_red16(stp_dot(z3, qx, qy, qz, qw));
      if (jc == 0) {
        float4 yo;  // y_stp = p*8 (undo qb's 0.125, exact pow2)
        yo.x = p0 * 8.f; yo.y = p1 * 8.f; yo.z = p2 * 8.f; yo.w = p3 * 8.f;
        *(float4*)&ylds[t * 64 + i0m] = yo;
      }
    }
  }

  __syncthreads();  // all waves' y_stp strips visible

  // Coalesced blend epilogue: 1024 float4-groups over 256 threads.
#pragma unroll
  for (int k2 = 0; k2 < 4; ++k2) {
    const int gi = k2 * 256 + tid;   // 0..1023
    const int t = gi >> 4;           // token within chunk
    const int d4 = (gi & 15) * 4;    // dim group
    const int ll = c * 64 + t;
    const int rowg = bh * L_ + ll;
    float m1 = mlb[rowg],          l1 = mlb[65536 + rowg];
    float m2 = mlb[131072 + rowg], l2 = mlb[196608 + rowg];
    float mm = fmaxf(m1, m2);
    float e1 = __expf(m1 - mm), e2 = __expf(m2 - mm);
    float inv = 1.f / fmaf(l1, e1, l2 * e2);
    float w1v = l1 * e1 * inv, w2v = l2 * e2 * inv;
    size_t bi = (size_t)rowg * 64 + d4;
    ushort4 o1u = *(const ushort4*)(osmb + bi);
    ushort4 o2u = *(const ushort4*)(osmb + 4194304 + bi);
    const int mtok = bb * L_ + ll;
    float a = alp[mtok * 16 + hh];
    const float na = 1.f - a;
    float4 ys = *(const float4*)&ylds[t * 64 + d4];
    ushort4 oo;
    oo.x = f2bf(a * (w1v * bf2f(o1u.x) + w2v * bf2f(o2u.x)) + na * ys.x);
    oo.y = f2bf(a * (w1v * bf2f(o1u.y) + w2v * bf2f(o2u.y)) + na * ys.y);
    oo.z = f2bf(a * (w1v * bf2f(o1u.z) + w2v * bf2f(o2u.z)) + na * ys.z);
    oo.w = f2bf(a * (w1v * bf2f(o1u.w) + w2v * bf2f(o2u.w)) + na * ys.w);
    *(ushort4*)(ycomb + (size_t)mtok * 1024 + hh * 64 + d4) = oo;
  }
}

// ---------------- launch ----------------

extern "C" void kernel_launch(void* const* d_in, const int* in_sizes, int n_in,
                              void* d_out, int out_size, void* d_ws, size_t ws_size,
                              hipStream_t stream) {
  const float* x       = (const float*)d_in[0];
  const float* wqkv_w  = (const float*)d_in[1];
  const float* wqkv_b  = (const float*)d_in[2];
  const float* out_w   = (const float*)d_in[3];
  const float* out_b   = (const float*)d_in[4];
  const float* w_stat  = (const float*)d_in[5];
  const float* lam     = (const float*)d_in[6];
  const float* gma     = (const float*)d_in[7];
  const float* g_w1    = (const float*)d_in[8];
  const float* g_b1    = (const float*)d_in[9];
  const float* g_w2    = (const float*)d_in[10];
  const float* g_b2    = (const float*)d_in[11];

  char* ws = (char*)d_ws;
  size_t off = 0;
  auto nxt = [&](size_t b) { size_t r = off; off += (b + 255) & ~(size_t)255; return r; };
  u16*   xbf   = (u16*)(ws + nxt((size_t)4096 * 1024 * 2));
  u16*   wqkvT = (u16*)(ws + nxt((size_t)3072 * 1024 * 2));
  u16*   owT   = (u16*)(ws + nxt((size_t)1024 * 1024 * 2));
  u16*   g1T   = (u16*)(ws + nxt((size_t)512 * 1024 * 2));
  u16*   qb    = (u16*)(ws + nxt((size_t)4194304 * 2));
  u16*   kb    = (u16*)(ws + nxt((size_t)4194304 * 2));
  u16*   vtb   = (u16*)(ws + nxt((size_t)4194304 * 2));
  u16*   osmb  = (u16*)(ws + nxt((size_t)2 * 4194304 * 2));   // 2 halves, bf16 O/l
  float* mlb   = (float*)(ws + nxt((size_t)4 * 65536 * 4));   // m/l per half
  // NO aliases: hbuf, ycomb, slocal all private.
  float* hbuf  = (float*)(ws + nxt((size_t)4096 * 512 * 4));   // 8MB
  u16*   ycomb = (u16*)(ws + nxt((size_t)4096 * 1024 * 2));    // 8MB
  float* slocal= (float*)(ws + nxt((size_t)4194304 * 4));      // 16MB
  float* alp   = (float*)(ws + nxt((size_t)4096 * 16 * 4));
  float* retb  = (float*)(ws + nxt((size_t)65536 * 4));
  float* gamb  = (float*)(ws + nxt((size_t)65536 * 4));
  float* retb64= (float*)(ws + nxt((size_t)65536 * 4));

  dim3 blk(256);
  prep_fused<<<8960, blk, 0, stream>>>(x, xbf, wqkv_w, wqkvT, out_w, owT,
                                       g_w1, g1T, lam, gma, retb, gamb, retb64);

  GemmP p0 = {xbf, wqkvT, 4096, 3072, 1024, wqkv_b,
              qb, kb, vtb, nullptr, nullptr};
  GemmP p1 = {xbf, g1T, 4096, 512, 1024, g_b1,
              nullptr, nullptr, nullptr, hbuf, nullptr};
  gemm01_kernel<<<1792, blk, 0, stream>>>(p0, p1);

  alpha_kernel<<<256, blk, 0, stream>>>(hbuf, g_w2, g_b2, alp);

  // attn split-kv KVBLK=128 (2048) + stp_pass1 (1024)
  attn_stp1_kernel<<<3072, blk, 0, stream>>>(qb, kb, vtb, osmb, mlb,
                                             retb, gamb, slocal);

  stp_scan<<<512, blk, 0, stream>>>(retb64, slocal);

  // pass2 with LDS-staged fused blend: writes ycomb directly.
  stp_pass2<<<1024, blk, 0, stream>>>(qb, kb, vtb, retb, gamb, w_stat,
                                      slocal, osmb, mlb, alp, ycomb);

  GemmP p2 = {ycomb, owT, 4096, 1024, 1024, out_b,
              nullptr, nullptr, nullptr, nullptr, (float*)d_out};
  gemm2_kernel<<<512, blk, 0, stream>>>(p2);
}